// Round 1
// baseline (3643.350 us; speedup 1.0000x reference)
//
#include <hip/hip_runtime.h>

#define D_IN   2048
#define D_SAE  16384
#define BATCH  4096
#define CAP    256      // max compacted nonzeros per row (k=64 + ties; kth=0 is statistically impossible here)

// ---------------------------------------------------------------------------
// K0: transpose W_dec (D_IN x D_SAE) -> W_decT (D_SAE x D_IN) in workspace
// ---------------------------------------------------------------------------
__global__ __launch_bounds__(256) void transpose_wdec(const float* __restrict__ W_dec,
                                                      float* __restrict__ W_decT) {
    __shared__ float t[32][33];
    int x0 = blockIdx.x * 32;           // col in W_dec (s / feature)
    int y0 = blockIdx.y * 32;           // row in W_dec (i / d_in)
    int tx = threadIdx.x;               // 0..31
    int ty = threadIdx.y;               // 0..7
    #pragma unroll
    for (int r = ty; r < 32; r += 8)
        t[r][tx] = W_dec[(long)(y0 + r) * D_SAE + (x0 + tx)];
    __syncthreads();
    #pragma unroll
    for (int r = ty; r < 32; r += 8)
        W_decT[(long)(x0 + r) * D_IN + (y0 + tx)] = t[tx][r];
}

// ---------------------------------------------------------------------------
// K1: codes_raw[b][s] = relu( dot(x[b,:], W_enc[s,:]) + b_enc[s] - tau[s] )
// f32 vector GEMM, NT layout (both operands row-major along K).
// 128x128 tile, BK=16, 256 threads, 8x8 outputs/thread.
// ---------------------------------------------------------------------------
#define BM 128
#define BN 128
#define BK 16
#define LDT (BM + 4)   // pad keeps 16B alignment (132*4B = 33*16B) and breaks pow2 strides

__global__ __launch_bounds__(256) void gemm_enc(const float* __restrict__ x,
                                                const float* __restrict__ W_enc,
                                                const float* __restrict__ b_enc,
                                                const float* __restrict__ tau,
                                                float* __restrict__ codes_raw) {
    __shared__ float As[BK][LDT];
    __shared__ float Bs[BK][LDT];
    const int tid = threadIdx.x;
    const int b0 = blockIdx.y * BM;
    const int s0 = blockIdx.x * BN;
    const int tx = tid & 15;
    const int ty = tid >> 4;

    float acc[8][8] = {};

    const float* xg = x     + (long)b0 * D_IN;
    const float* wg = W_enc + (long)s0 * D_IN;

    for (int k0 = 0; k0 < D_IN; k0 += BK) {
        // stage tiles: 128 rows x 16 k = 512 float4 per operand, 2 float4/thread
        #pragma unroll
        for (int p = 0; p < 2; ++p) {
            int f   = tid + p * 256;
            int row = f >> 2;
            int kq  = (f & 3) * 4;
            float4 va = *(const float4*)(xg + (long)row * D_IN + k0 + kq);
            As[kq + 0][row] = va.x; As[kq + 1][row] = va.y;
            As[kq + 2][row] = va.z; As[kq + 3][row] = va.w;
            float4 vb = *(const float4*)(wg + (long)row * D_IN + k0 + kq);
            Bs[kq + 0][row] = vb.x; Bs[kq + 1][row] = vb.y;
            Bs[kq + 2][row] = vb.z; Bs[kq + 3][row] = vb.w;
        }
        __syncthreads();
        #pragma unroll
        for (int kk = 0; kk < BK; ++kk) {
            float a[8], b[8];
            *(float4*)&a[0] = *(const float4*)&As[kk][ty * 8];
            *(float4*)&a[4] = *(const float4*)&As[kk][ty * 8 + 4];
            *(float4*)&b[0] = *(const float4*)&Bs[kk][tx * 8];
            *(float4*)&b[4] = *(const float4*)&Bs[kk][tx * 8 + 4];
            #pragma unroll
            for (int i = 0; i < 8; ++i)
                #pragma unroll
                for (int j = 0; j < 8; ++j)
                    acc[i][j] = fmaf(a[i], b[j], acc[i][j]);
        }
        __syncthreads();
    }

    // epilogue: + b_enc, relu(pre - tau). Raw codes -> d_out codes region.
    const int sc = s0 + tx * 8;
    float4 be0 = *(const float4*)(b_enc + sc);
    float4 be1 = *(const float4*)(b_enc + sc + 4);
    float4 tv0 = *(const float4*)(tau + sc);
    float4 tv1 = *(const float4*)(tau + sc + 4);
    #pragma unroll
    for (int i = 0; i < 8; ++i) {
        int b = b0 + ty * 8 + i;
        float4 o0, o1;
        o0.x = fmaxf(acc[i][0] + be0.x - tv0.x, 0.f);
        o0.y = fmaxf(acc[i][1] + be0.y - tv0.y, 0.f);
        o0.z = fmaxf(acc[i][2] + be0.z - tv0.z, 0.f);
        o0.w = fmaxf(acc[i][3] + be0.w - tv0.w, 0.f);
        o1.x = fmaxf(acc[i][4] + be1.x - tv1.x, 0.f);
        o1.y = fmaxf(acc[i][5] + be1.y - tv1.y, 0.f);
        o1.z = fmaxf(acc[i][6] + be1.z - tv1.z, 0.f);
        o1.w = fmaxf(acc[i][7] + be1.w - tv1.w, 0.f);
        long ob = (long)b * D_SAE + sc;
        *(float4*)(codes_raw + ob)     = o0;
        *(float4*)(codes_raw + ob + 4) = o1;
    }
}

// ---------------------------------------------------------------------------
// K2: per-row exact rank-K select (binary search on float bit patterns —
// monotone for non-negative floats, exact with ties), then apply mask_k,
// write final codes + mask, and compact (idx,val) deterministically.
// One block (256 threads) per row; row lives in 64 registers/thread.
// ---------------------------------------------------------------------------
__global__ __launch_bounds__(256) void select_apply(float* __restrict__ codes,
                                                    float* __restrict__ mask,
                                                    const int* __restrict__ kptr,
                                                    int* __restrict__ cnt_out,
                                                    int* __restrict__ idx_out,
                                                    float* __restrict__ val_out) {
    const int row = blockIdx.x;
    const int tid = threadIdx.x;
    const long base = (long)row * D_SAE;

    // element s = i*1024 + tid*4 + j   (i<16, j<4) — float4 coalesced
    unsigned v[16][4];
    #pragma unroll
    for (int i = 0; i < 16; ++i) {
        uint4 u = *(const uint4*)(codes + base + i * 1024 + tid * 4);
        v[i][0] = u.x; v[i][1] = u.y; v[i][2] = u.z; v[i][3] = u.w;
    }

    int K = kptr[0];
    if (K > D_SAE) K = D_SAE;

    __shared__ int wsum[4];
    __shared__ int scan[256];

    // binary search: invariant count(>= lo) >= K, count(>= hi) < K
    unsigned lo = 0u, hi = 0x7F800000u;  // [ +0, +inf )
    while (hi - lo > 1u) {
        unsigned mid = lo + ((hi - lo) >> 1);
        int c = 0;
        #pragma unroll
        for (int i = 0; i < 16; ++i)
            #pragma unroll
            for (int j = 0; j < 4; ++j)
                c += (v[i][j] >= mid);
        #pragma unroll
        for (int off = 32; off; off >>= 1) c += __shfl_xor(c, off, 64);
        if ((tid & 63) == 0) wsum[tid >> 6] = c;
        __syncthreads();
        int tot = wsum[0] + wsum[1] + wsum[2] + wsum[3];
        __syncthreads();
        if (tot >= K) lo = mid; else hi = mid;
    }
    const unsigned kb = lo;   // bit pattern of kth value

    // per-thread keep count, deterministic prefix scan over tid
    int kc = 0;
    #pragma unroll
    for (int i = 0; i < 16; ++i)
        #pragma unroll
        for (int j = 0; j < 4; ++j)
            kc += (v[i][j] >= kb) && (v[i][j] != 0u);
    scan[tid] = kc;
    __syncthreads();
    #pragma unroll
    for (int off = 1; off < 256; off <<= 1) {
        int a = scan[tid];
        int b = (tid >= off) ? scan[tid - off] : 0;
        __syncthreads();
        scan[tid] = a + b;
        __syncthreads();
    }
    int pos   = scan[tid] - kc;      // exclusive prefix
    int total = scan[255];

    // write final codes + mask, append compacted entries
    #pragma unroll
    for (int i = 0; i < 16; ++i) {
        float4 cf; float4 mf;
        #pragma unroll
        for (int j = 0; j < 4; ++j) {
            unsigned b = v[i][j];
            bool keep = (b >= kb);
            bool m    = keep && (b != 0u);   // c > 0 (non-negative floats)
            float c   = __uint_as_float(b);
            float cv  = keep ? c : 0.f;
            ((float*)&cf)[j] = cv;
            ((float*)&mf)[j] = m ? 1.f : 0.f;
            if (m) {
                if (pos < CAP) {
                    idx_out[row * CAP + pos] = i * 1024 + tid * 4 + j;
                    val_out[row * CAP + pos] = cv;
                }
                ++pos;
            }
        }
        long o = base + i * 1024 + tid * 4;
        *(float4*)(codes + o) = cf;
        *(float4*)(mask  + o) = mf;
    }
    if (tid == 0) cnt_out[row] = total < CAP ? total : CAP;
}

// ---------------------------------------------------------------------------
// K3: recon[b,:] = sum_j val_j * W_decT[idx_j, :]   (~64 coalesced row reads)
// One block per batch row; each thread owns 2 float4 (8 of 2048 outputs).
// ---------------------------------------------------------------------------
__global__ __launch_bounds__(256) void recon_sparse(const float* __restrict__ W_decT,
                                                    const int* __restrict__ cnt,
                                                    const int* __restrict__ idx,
                                                    const float* __restrict__ val,
                                                    float* __restrict__ recon) {
    const int row = blockIdx.x;
    const int tid = threadIdx.x;
    __shared__ int   s_idx[CAP];
    __shared__ float s_val[CAP];
    const int n = cnt[row];
    for (int j = tid; j < n; j += 256) {
        s_idx[j] = idx[row * CAP + j];
        s_val[j] = val[row * CAP + j];
    }
    __syncthreads();

    float4 a0 = {0.f, 0.f, 0.f, 0.f};
    float4 a1 = {0.f, 0.f, 0.f, 0.f};
    for (int j = 0; j < n; ++j) {
        float c = s_val[j];
        const float4* w = (const float4*)(W_decT + (long)s_idx[j] * D_IN);
        float4 w0 = w[tid];
        float4 w1 = w[tid + 256];
        a0.x = fmaf(c, w0.x, a0.x); a0.y = fmaf(c, w0.y, a0.y);
        a0.z = fmaf(c, w0.z, a0.z); a0.w = fmaf(c, w0.w, a0.w);
        a1.x = fmaf(c, w1.x, a1.x); a1.y = fmaf(c, w1.y, a1.y);
        a1.z = fmaf(c, w1.z, a1.z); a1.w = fmaf(c, w1.w, a1.w);
    }
    float4* out = (float4*)(recon + (long)row * D_IN);
    out[tid]       = a0;
    out[tid + 256] = a1;
}

// ---------------------------------------------------------------------------
extern "C" void kernel_launch(void* const* d_in, const int* in_sizes, int n_in,
                              void* d_out, int out_size, void* d_ws, size_t ws_size,
                              hipStream_t stream) {
    const float* x     = (const float*)d_in[0];
    const float* W_enc = (const float*)d_in[1];
    const float* b_enc = (const float*)d_in[2];
    const float* tau   = (const float*)d_in[3];
    const float* W_dec = (const float*)d_in[4];
    const int*   kptr  = (const int*)d_in[5];

    float* recon = (float*)d_out;                       // BATCH * D_IN
    float* codes = recon + (long)BATCH * D_IN;          // BATCH * D_SAE
    float* maskp = codes + (long)BATCH * D_SAE;         // BATCH * D_SAE

    // workspace layout (needs ~142.6 MB)
    char*  w      = (char*)d_ws;
    float* W_decT = (float*)w;                                              // 134217728 B
    int*   cnt    = (int*)  (w + (size_t)134217728);                        // 16 KB
    int*   idxl   = (int*)  (w + (size_t)134217728 + 16384);                // 4 MB
    float* vall   = (float*)(w + (size_t)134217728 + 16384 + (size_t)BATCH * CAP * 4); // 4 MB

    hipLaunchKernelGGL(transpose_wdec, dim3(D_SAE / 32, D_IN / 32), dim3(32, 8), 0, stream,
                       W_dec, W_decT);
    hipLaunchKernelGGL(gemm_enc, dim3(D_SAE / BN, BATCH / BM), dim3(256), 0, stream,
                       x, W_enc, b_enc, tau, codes);
    hipLaunchKernelGGL(select_apply, dim3(BATCH), dim3(256), 0, stream,
                       codes, maskp, kptr, cnt, idxl, vall);
    hipLaunchKernelGGL(recon_sparse, dim3(BATCH), dim3(256), 0, stream,
                       W_decT, cnt, idxl, vall, recon);
}

// Round 3
// 1546.481 us; speedup vs baseline: 2.3559x; 2.3559x over previous
//
#include <hip/hip_runtime.h>

#define D_IN   2048
#define D_SAE  16384
#define BATCH  4096
#define CAP    256      // max compacted nonzeros per row
#define MAXB   64       // max boundary-band candidates per row

typedef __attribute__((ext_vector_type(8))) short bf16x8;
typedef __attribute__((ext_vector_type(4))) float f32x4;

// ---------------------------------------------------------------------------
// K0: split f32 -> (hi, lo) bf16 pair, RN each step. x = hi + lo + r, |r| <= 2^-18|x|
// ---------------------------------------------------------------------------
__global__ __launch_bounds__(256) void split_hi_lo(const float* __restrict__ in,
                                                   ushort* __restrict__ hi,
                                                   ushort* __restrict__ lo, int n4) {
    int i = blockIdx.x * blockDim.x + threadIdx.x;
    int stride = gridDim.x * blockDim.x;
    for (; i < n4; i += stride) {
        float4 v = ((const float4*)in)[i];
        ushort4 h, l;
        float*  vp = (float*)&v;
        ushort* hp = (ushort*)&h;
        ushort* lp = (ushort*)&l;
        #pragma unroll
        for (int j = 0; j < 4; ++j) {
            float xf = vp[j];
            unsigned u  = __float_as_uint(xf);
            unsigned hb = (u + 0x7FFFu + ((u >> 16) & 1u)) >> 16;
            float hf = __uint_as_float(hb << 16);
            float rf = xf - hf;
            unsigned r  = __float_as_uint(rf);
            unsigned lb = (r + 0x7FFFu + ((r >> 16) & 1u)) >> 16;
            hp[j] = (ushort)hb;
            lp[j] = (ushort)lb;
        }
        ((ushort4*)hi)[i] = h;
        ((ushort4*)lo)[i] = l;
    }
}

// ---------------------------------------------------------------------------
// K1: codes[b][s] = relu( x·W_enc[s] + b_enc[s] - tau[s] ), bf16x3 MFMA.
// 128x128 tile, BK=32, 4 waves (64x64 each), global_load_lds staging.
// ---------------------------------------------------------------------------
__device__ __forceinline__ void async_copy16(const void* g, void* l) {
    __builtin_amdgcn_global_load_lds(
        (const __attribute__((address_space(1))) unsigned int*)g,
        (__attribute__((address_space(3))) unsigned int*)l, 16, 0, 0);
}

__global__ __launch_bounds__(256) void gemm_enc_mfma(
        const ushort* __restrict__ xsp,
        const ushort* __restrict__ wsp,
        const float* __restrict__ b_enc,
        const float* __restrict__ tau,
        float* __restrict__ codes) {
    __shared__ __align__(16) ushort lds[4][128][32];   // A_hi, A_lo, B_hi, B_lo
    const int tid  = threadIdx.x;
    const int wid  = tid >> 6;
    const int lane = tid & 63;
    const int m0 = blockIdx.x * 128;
    const int s0 = blockIdx.y * 128;
    const int wm = wid >> 1, wn = wid & 1;

    const ushort* x_hi = xsp;
    const ushort* x_lo = xsp + (size_t)BATCH * D_IN;
    const ushort* w_hi = wsp;
    const ushort* w_lo = wsp + (size_t)D_SAE * D_IN;

    const ushort* gbase;
    if      (wid == 0) gbase = x_hi + (size_t)m0 * D_IN;
    else if (wid == 1) gbase = x_lo + (size_t)m0 * D_IN;
    else if (wid == 2) gbase = w_hi + (size_t)s0 * D_IN;
    else               gbase = w_lo + (size_t)s0 * D_IN;
    const ushort* gthread = gbase + (size_t)(lane >> 2) * D_IN + (lane & 3) * 8;

    f32x4 acc[4][4] = {};

    const int fr = lane & 15;
    const int fk = (lane >> 4) * 8;

    for (int k0 = 0; k0 < D_IN; k0 += 32) {
        #pragma unroll
        for (int i = 0; i < 8; ++i)
            async_copy16(gthread + (size_t)i * 16 * D_IN + k0, &lds[wid][i * 16][0]);
        __syncthreads();

        bf16x8 ah[4], al[4], bh[4], bl[4];
        #pragma unroll
        for (int f = 0; f < 4; ++f) {
            int ar = wm * 64 + f * 16 + fr;
            int bc = wn * 64 + f * 16 + fr;
            ah[f] = *(const bf16x8*)&lds[0][ar][fk];
            al[f] = *(const bf16x8*)&lds[1][ar][fk];
            bh[f] = *(const bf16x8*)&lds[2][bc][fk];
            bl[f] = *(const bf16x8*)&lds[3][bc][fk];
        }
        #pragma unroll
        for (int i = 0; i < 4; ++i)
            #pragma unroll
            for (int j = 0; j < 4; ++j) {
                acc[i][j] = __builtin_amdgcn_mfma_f32_16x16x32_bf16(ah[i], bh[j], acc[i][j], 0, 0, 0);
                acc[i][j] = __builtin_amdgcn_mfma_f32_16x16x32_bf16(ah[i], bl[j], acc[i][j], 0, 0, 0);
                acc[i][j] = __builtin_amdgcn_mfma_f32_16x16x32_bf16(al[i], bh[j], acc[i][j], 0, 0, 0);
            }
        __syncthreads();
    }

    const int fq = lane >> 4;
    #pragma unroll
    for (int j = 0; j < 4; ++j) {
        int col = s0 + wn * 64 + j * 16 + fr;
        float be = b_enc[col] - tau[col];
        #pragma unroll
        for (int i = 0; i < 4; ++i) {
            int rbase = m0 + wm * 64 + i * 16 + fq * 4;
            #pragma unroll
            for (int r = 0; r < 4; ++r) {
                float v = fmaxf(acc[i][j][r] + be, 0.f);
                codes[(size_t)(rbase + r) * D_SAE + col] = v;
            }
        }
    }
}

// ---------------------------------------------------------------------------
// K2: transpose W_dec -> W_decT
// ---------------------------------------------------------------------------
__global__ __launch_bounds__(256) void transpose_wdec(const float* __restrict__ W_dec,
                                                      float* __restrict__ W_decT) {
    __shared__ float t[32][33];
    int x0 = blockIdx.x * 32;
    int y0 = blockIdx.y * 32;
    int tx = threadIdx.x;
    int ty = threadIdx.y;
    #pragma unroll
    for (int r = ty; r < 32; r += 8)
        t[r][tx] = W_dec[(long)(y0 + r) * D_SAE + (x0 + tx)];
    __syncthreads();
    #pragma unroll
    for (int r = ty; r < 32; r += 8)
        W_decT[(long)(x0 + r) * D_IN + (y0 + tx)] = t[tx][r];
}

// ---------------------------------------------------------------------------
// K3: exact rank-K select with f64 band refinement.
//  1) binary search kth on approx codes (bit patterns)
//  2) band = |c - kth| <= DELTA; recompute those pre's exactly in f64
//  3) select top (K - n_above) of band by exact value
//  4) write final codes/mask, compact (idx,val) deterministically
// ---------------------------------------------------------------------------
#define DELTA 1e-3f

__global__ __launch_bounds__(256) void select_apply(
        float* __restrict__ codes, float* __restrict__ mask,
        const int* __restrict__ kptr,
        const float* __restrict__ x, const float* __restrict__ W_enc,
        const float* __restrict__ b_enc, const float* __restrict__ tau,
        int* __restrict__ cnt_out, int* __restrict__ idx_out,
        float* __restrict__ val_out) {
    const int row = blockIdx.x;
    const int tid = threadIdx.x;
    const long base = (long)row * D_SAE;

    unsigned v[16][4];
    #pragma unroll
    for (int i = 0; i < 16; ++i) {
        uint4 u = *(const uint4*)(codes + base + i * 1024 + tid * 4);
        v[i][0] = u.x; v[i][1] = u.y; v[i][2] = u.z; v[i][3] = u.w;
    }

    int K = kptr[0];
    if (K > D_SAE) K = D_SAE;

    __shared__ int    wsum[4];
    __shared__ int    scan[256];
    __shared__ int    bidx[MAXB];
    __shared__ double exactv[MAXB];
    __shared__ int    selfl[MAXB];
    __shared__ double dsum[4];

    // --- 1) binary search on bit patterns (monotone for non-negative floats)
    unsigned lo = 0u, hi = 0x7F800000u;
    while (hi - lo > 1u) {
        unsigned mid = lo + ((hi - lo) >> 1);
        int c = 0;
        #pragma unroll
        for (int i = 0; i < 16; ++i)
            #pragma unroll
            for (int j = 0; j < 4; ++j)
                c += (v[i][j] >= mid);
        #pragma unroll
        for (int off = 32; off; off >>= 1) c += __shfl_xor(c, off, 64);
        if ((tid & 63) == 0) wsum[tid >> 6] = c;
        __syncthreads();
        int tot = wsum[0] + wsum[1] + wsum[2] + wsum[3];
        __syncthreads();
        if (tot >= K) lo = mid; else hi = mid;
    }
    const float kf = __uint_as_float(lo);
    const float thr_hi = kf + DELTA;
    const float thr_lo = kf - DELTA;

    // --- 2) count above / band
    int cA = 0, cB = 0;
    #pragma unroll
    for (int i = 0; i < 16; ++i)
        #pragma unroll
        for (int j = 0; j < 4; ++j) {
            float c = __uint_as_float(v[i][j]);
            cA += (c > thr_hi);
            cB += (c >= thr_lo) && (c <= thr_hi);
        }
    {
        int a = cA;
        #pragma unroll
        for (int off = 32; off; off >>= 1) a += __shfl_xor(a, off, 64);
        if ((tid & 63) == 0) wsum[tid >> 6] = a;
    }
    __syncthreads();
    const int nA = wsum[0] + wsum[1] + wsum[2] + wsum[3];
    __syncthreads();

    // band prefix scan -> deterministic slots
    scan[tid] = cB;
    __syncthreads();
    #pragma unroll
    for (int off = 1; off < 256; off <<= 1) {
        int a = scan[tid];
        int b = (tid >= off) ? scan[tid - off] : 0;
        __syncthreads();
        scan[tid] = a + b;
        __syncthreads();
    }
    int posB = scan[tid] - cB;
    int nb   = scan[255];
    if (nb > MAXB) nb = MAXB;

    {
        int p = posB;
        #pragma unroll
        for (int i = 0; i < 16; ++i)
            #pragma unroll
            for (int j = 0; j < 4; ++j) {
                float c = __uint_as_float(v[i][j]);
                if ((c >= thr_lo) && (c <= thr_hi)) {
                    if (p < MAXB) bidx[p] = i * 1024 + tid * 4 + j;
                    ++p;
                }
            }
    }
    __syncthreads();

    // --- 3) exact f64 pre for band candidates (block-cooperative, deterministic)
    const float* xrow = x + (size_t)row * D_IN;
    for (int jj = 0; jj < nb; ++jj) {
        int s = bidx[jj];
        const float* wrow = W_enc + (size_t)s * D_IN;
        double a = 0.0;
        #pragma unroll
        for (int q = 0; q < 8; ++q)
            a += (double)xrow[tid * 8 + q] * (double)wrow[tid * 8 + q];
        #pragma unroll
        for (int off = 32; off; off >>= 1) a += __shfl_xor(a, off, 64);
        if ((tid & 63) == 0) dsum[tid >> 6] = a;
        __syncthreads();
        if (tid == 0)
            exactv[jj] = dsum[0] + dsum[1] + dsum[2] + dsum[3]
                         + (double)b_enc[s] - (double)tau[s];
        __syncthreads();
    }

    int m = K - nA;            // band slots to fill (>=1, <= nb)
    if (m > nb) m = nb;
    if (tid < nb) {
        double e = exactv[tid];
        int rank = 0;
        for (int l = 0; l < nb; ++l) rank += (exactv[l] > e);
        selfl[tid] = (rank < m) ? 1 : 0;
    }
    __syncthreads();

    // per-thread override bits for owned band elements (owner tid = (s>>2)&255)
    unsigned ov0 = 0u, ov1 = 0u;
    for (int jj = 0; jj < nb; ++jj) {
        int s = bidx[jj];
        if (((s >> 2) & 255) == tid && selfl[jj]) {
            int b = (s >> 10) * 4 + (s & 3);
            if (b < 32) ov0 |= 1u << b; else ov1 |= 1u << (b - 32);
        }
    }

    // --- 4) final keep predicate, compaction scan, writes
    int kc = 0;
    #pragma unroll
    for (int i = 0; i < 16; ++i)
        #pragma unroll
        for (int j = 0; j < 4; ++j) {
            float c = __uint_as_float(v[i][j]);
            int b = i * 4 + j;
            bool sel = (c > thr_hi) || ((b < 32 ? (ov0 >> b) : (ov1 >> (b - 32))) & 1);
            kc += sel && (c > 0.f);
        }
    __syncthreads();
    scan[tid] = kc;
    __syncthreads();
    #pragma unroll
    for (int off = 1; off < 256; off <<= 1) {
        int a = scan[tid];
        int b = (tid >= off) ? scan[tid - off] : 0;
        __syncthreads();
        scan[tid] = a + b;
        __syncthreads();
    }
    int pos   = scan[tid] - kc;
    int total = scan[255];

    #pragma unroll
    for (int i = 0; i < 16; ++i) {
        float4 cf; float4 mf;
        #pragma unroll
        for (int j = 0; j < 4; ++j) {
            float c = __uint_as_float(v[i][j]);
            int b = i * 4 + j;
            bool sel = (c > thr_hi) || ((b < 32 ? (ov0 >> b) : (ov1 >> (b - 32))) & 1);
            bool m_  = sel && (c > 0.f);
            float cv = sel ? c : 0.f;
            ((float*)&cf)[j] = cv;
            ((float*)&mf)[j] = m_ ? 1.f : 0.f;
            if (m_) {
                if (pos < CAP) {
                    idx_out[row * CAP + pos] = i * 1024 + tid * 4 + j;
                    val_out[row * CAP + pos] = cv;
                }
                ++pos;
            }
        }
        long o = base + i * 1024 + tid * 4;
        *(float4*)(codes + o) = cf;
        *(float4*)(mask  + o) = mf;
    }
    if (tid == 0) cnt_out[row] = total < CAP ? total : CAP;
}

// ---------------------------------------------------------------------------
// K4: recon[b,:] = sum_j val_j * W_decT[idx_j, :]
// ---------------------------------------------------------------------------
__global__ __launch_bounds__(256) void recon_sparse(const float* __restrict__ W_decT,
                                                    const int* __restrict__ cnt,
                                                    const int* __restrict__ idx,
                                                    const float* __restrict__ val,
                                                    float* __restrict__ recon) {
    const int row = blockIdx.x;
    const int tid = threadIdx.x;
    __shared__ int   s_idx[CAP];
    __shared__ float s_val[CAP];
    const int n = cnt[row];
    for (int j = tid; j < n; j += 256) {
        s_idx[j] = idx[row * CAP + j];
        s_val[j] = val[row * CAP + j];
    }
    __syncthreads();

    float4 a0 = {0.f, 0.f, 0.f, 0.f};
    float4 a1 = {0.f, 0.f, 0.f, 0.f};
    for (int j = 0; j < n; ++j) {
        float c = s_val[j];
        const float4* w = (const float4*)(W_decT + (long)s_idx[j] * D_IN);
        float4 w0 = w[tid];
        float4 w1 = w[tid + 256];
        a0.x = fmaf(c, w0.x, a0.x); a0.y = fmaf(c, w0.y, a0.y);
        a0.z = fmaf(c, w0.z, a0.z); a0.w = fmaf(c, w0.w, a0.w);
        a1.x = fmaf(c, w1.x, a1.x); a1.y = fmaf(c, w1.y, a1.y);
        a1.z = fmaf(c, w1.z, a1.z); a1.w = fmaf(c, w1.w, a1.w);
    }
    float4* out = (float4*)(recon + (long)row * D_IN);
    out[tid]       = a0;
    out[tid + 256] = a1;
}

// ---------------------------------------------------------------------------
// Workspace (peak 160 MiB), phase-overlapped:
//   phase A: [0,128M) w_hi|w_lo ; [128M,160M) x_hi|x_lo
//   phase B: [0,128M) W_decT ; [128M,...) cnt/idx/val
// ---------------------------------------------------------------------------
extern "C" void kernel_launch(void* const* d_in, const int* in_sizes, int n_in,
                              void* d_out, int out_size, void* d_ws, size_t ws_size,
                              hipStream_t stream) {
    const float* x     = (const float*)d_in[0];
    const float* W_enc = (const float*)d_in[1];
    const float* b_enc = (const float*)d_in[2];
    const float* tau   = (const float*)d_in[3];
    const float* W_dec = (const float*)d_in[4];
    const int*   kptr  = (const int*)d_in[5];

    float* recon = (float*)d_out;
    float* codes = recon + (size_t)BATCH * D_IN;
    float* maskp = codes + (size_t)BATCH * D_SAE;

    char* w = (char*)d_ws;
    const size_t W_SPLIT = (size_t)D_SAE * D_IN * 2;
    ushort* w_split = (ushort*)w;
    ushort* x_split = (ushort*)(w + 2 * W_SPLIT);
    float*  W_decT  = (float*)w;
    int*    cnt     = (int*)  (w + 2 * W_SPLIT);
    int*    idxl    = (int*)  (w + 2 * W_SPLIT + 16384);
    float*  vall    = (float*)(w + 2 * W_SPLIT + 16384 + (size_t)BATCH * CAP * 4);

    ushort* x_hi = x_split;
    ushort* x_lo = x_split + (size_t)BATCH * D_IN;
    ushort* w_hi = w_split;
    ushort* w_lo = w_split + (size_t)D_SAE * D_IN;

    hipLaunchKernelGGL(split_hi_lo, dim3(1024), dim3(256), 0, stream,
                       x, x_hi, x_lo, BATCH * D_IN / 4);
    hipLaunchKernelGGL(split_hi_lo, dim3(2048), dim3(256), 0, stream,
                       W_enc, w_hi, w_lo, D_SAE * D_IN / 4);
    hipLaunchKernelGGL(gemm_enc_mfma, dim3(BATCH / 128, D_SAE / 128), dim3(256), 0, stream,
                       x_split, w_split, b_enc, tau, codes);
    hipLaunchKernelGGL(select_apply, dim3(BATCH), dim3(256), 0, stream,
                       codes, maskp, kptr, x, W_enc, b_enc, tau, cnt, idxl, vall);
    hipLaunchKernelGGL(transpose_wdec, dim3(D_SAE / 32, D_IN / 32), dim3(32, 8), 0, stream,
                       W_dec, W_decT);
    hipLaunchKernelGGL(recon_sparse, dim3(BATCH), dim3(256), 0, stream,
                       W_decT, cnt, idxl, vall, recon);
}

// Round 4
// 1043.352 us; speedup vs baseline: 3.4920x; 1.4822x over previous
//
#include <hip/hip_runtime.h>

#define D_IN   2048
#define D_SAE  16384
#define BATCH  4096
#define CAP    256      // max compacted nonzeros per row
#define MAXB   64       // max boundary-band candidates per row
#define DELTA  6e-3f    // band half-width; >= 4x max f16-GEMM pre error

typedef __attribute__((ext_vector_type(8))) _Float16 f16x8;
typedef __attribute__((ext_vector_type(4))) float f32x4;

// ---------------------------------------------------------------------------
// K0: convert f32 -> f16 (RN). Error <= 2^-11 relative.
// ---------------------------------------------------------------------------
__global__ __launch_bounds__(256) void to_f16(const float* __restrict__ in,
                                              ushort* __restrict__ out, int n4) {
    int i = blockIdx.x * blockDim.x + threadIdx.x;
    int stride = gridDim.x * blockDim.x;
    for (; i < n4; i += stride) {
        float4 v = ((const float4*)in)[i];
        ushort4 h;
        float*  vp = (float*)&v;
        ushort* hp = (ushort*)&h;
        #pragma unroll
        for (int j = 0; j < 4; ++j) {
            _Float16 f = (_Float16)vp[j];
            hp[j] = *(ushort*)&f;
        }
        ((ushort4*)out)[i] = h;
    }
}

// ---------------------------------------------------------------------------
// K1: codes[b][s] = relu( x·W_enc[s] + b_enc[s] - tau[s] ), single f16 MFMA.
// m97 structure: 128x128 tile, BK=32, 4 waves (64x64 each), 16KB LDS,
// global_load_lds width-16 staging, 2-barrier K-loop.
// ---------------------------------------------------------------------------
__device__ __forceinline__ void async_copy16(const void* g, void* l) {
    __builtin_amdgcn_global_load_lds(
        (const __attribute__((address_space(1))) unsigned int*)g,
        (__attribute__((address_space(3))) unsigned int*)l, 16, 0, 0);
}

__global__ __launch_bounds__(256) void gemm_enc_mfma(
        const ushort* __restrict__ xh,    // x_f16 [4096][2048]
        const ushort* __restrict__ wh,    // w_f16 [16384][2048]
        const float* __restrict__ b_enc,
        const float* __restrict__ tau,
        float* __restrict__ codes) {
    __shared__ __align__(16) ushort lds[2][128][32];   // A, B = 16 KB
    const int tid  = threadIdx.x;
    const int wid  = tid >> 6;
    const int lane = tid & 63;
    const int m0 = blockIdx.x * 128;   // batch panel
    const int s0 = blockIdx.y * 128;   // feature panel
    const int wm = wid >> 1, wn = wid & 1;

    // staging: waves 0,1 -> A halves; waves 2,3 -> B halves. 4 loads/lane/step.
    const int arr  = wid >> 1;         // 0=A, 1=B
    const int half = wid & 1;          // row half
    const ushort* gsrc = (arr == 0) ? (xh + (size_t)m0 * D_IN)
                                    : (wh + (size_t)s0 * D_IN);
    const ushort* gthread = gsrc + (size_t)(half * 64 + (lane >> 2)) * D_IN + (lane & 3) * 8;

    f32x4 acc[4][4] = {};

    const int fr = lane & 15;
    const int fk = (lane >> 4) * 8;

    for (int k0 = 0; k0 < D_IN; k0 += 32) {
        #pragma unroll
        for (int r = 0; r < 4; ++r)
            async_copy16(gthread + (size_t)r * 16 * D_IN + k0,
                         &lds[arr][half * 64 + r * 16][0]);
        __syncthreads();

        f16x8 a[4], b[4];
        #pragma unroll
        for (int f = 0; f < 4; ++f) {
            a[f] = *(const f16x8*)&lds[0][wm * 64 + f * 16 + fr][fk];
            b[f] = *(const f16x8*)&lds[1][wn * 64 + f * 16 + fr][fk];
        }
        #pragma unroll
        for (int i = 0; i < 4; ++i)
            #pragma unroll
            for (int j = 0; j < 4; ++j)
                acc[i][j] = __builtin_amdgcn_mfma_f32_16x16x32_f16(a[i], b[j], acc[i][j], 0, 0, 0);
        __syncthreads();
    }

    // epilogue: + b_enc - tau, relu; C/D layout col=lane&15, row=(lane>>4)*4+reg
    const int fq = lane >> 4;
    #pragma unroll
    for (int j = 0; j < 4; ++j) {
        int col = s0 + wn * 64 + j * 16 + fr;
        float be = b_enc[col] - tau[col];
        #pragma unroll
        for (int i = 0; i < 4; ++i) {
            int rbase = m0 + wm * 64 + i * 16 + fq * 4;
            #pragma unroll
            for (int r = 0; r < 4; ++r) {
                float v = fmaxf(acc[i][j][r] + be, 0.f);
                codes[(size_t)(rbase + r) * D_SAE + col] = v;
            }
        }
    }
}

// ---------------------------------------------------------------------------
// K2: transpose W_dec -> W_decT
// ---------------------------------------------------------------------------
__global__ __launch_bounds__(256) void transpose_wdec(const float* __restrict__ W_dec,
                                                      float* __restrict__ W_decT) {
    __shared__ float t[32][33];
    int x0 = blockIdx.x * 32;
    int y0 = blockIdx.y * 32;
    int tx = threadIdx.x;
    int ty = threadIdx.y;
    #pragma unroll
    for (int r = ty; r < 32; r += 8)
        t[r][tx] = W_dec[(long)(y0 + r) * D_SAE + (x0 + tx)];
    __syncthreads();
    #pragma unroll
    for (int r = ty; r < 32; r += 8)
        W_decT[(long)(x0 + r) * D_IN + (y0 + tx)] = t[tx][r];
}

// ---------------------------------------------------------------------------
// K3: exact rank-K select with f64 band refinement (selection provably exact
// when DELTA >= 2 * max pre-error; here 4x margin).
// ---------------------------------------------------------------------------
__global__ __launch_bounds__(256) void select_apply(
        float* __restrict__ codes, float* __restrict__ mask,
        const int* __restrict__ kptr,
        const float* __restrict__ x, const float* __restrict__ W_enc,
        const float* __restrict__ b_enc, const float* __restrict__ tau,
        int* __restrict__ cnt_out, int* __restrict__ idx_out,
        float* __restrict__ val_out) {
    const int row = blockIdx.x;
    const int tid = threadIdx.x;
    const long base = (long)row * D_SAE;

    unsigned v[16][4];
    #pragma unroll
    for (int i = 0; i < 16; ++i) {
        uint4 u = *(const uint4*)(codes + base + i * 1024 + tid * 4);
        v[i][0] = u.x; v[i][1] = u.y; v[i][2] = u.z; v[i][3] = u.w;
    }

    int K = kptr[0];
    if (K > D_SAE) K = D_SAE;

    __shared__ int    wsum[4];
    __shared__ int    scan[256];
    __shared__ int    bidx[MAXB];
    __shared__ double exactv[MAXB];
    __shared__ int    selfl[MAXB];
    __shared__ double dsum[4];

    // --- 1) binary search kth on bit patterns
    unsigned lo = 0u, hi = 0x7F800000u;
    while (hi - lo > 1u) {
        unsigned mid = lo + ((hi - lo) >> 1);
        int c = 0;
        #pragma unroll
        for (int i = 0; i < 16; ++i)
            #pragma unroll
            for (int j = 0; j < 4; ++j)
                c += (v[i][j] >= mid);
        #pragma unroll
        for (int off = 32; off; off >>= 1) c += __shfl_xor(c, off, 64);
        if ((tid & 63) == 0) wsum[tid >> 6] = c;
        __syncthreads();
        int tot = wsum[0] + wsum[1] + wsum[2] + wsum[3];
        __syncthreads();
        if (tot >= K) lo = mid; else hi = mid;
    }
    const float kf = __uint_as_float(lo);
    const float thr_hi = kf + DELTA;
    const float thr_lo = kf - DELTA;

    // --- 2) count above / collect band
    int cA = 0, cB = 0;
    #pragma unroll
    for (int i = 0; i < 16; ++i)
        #pragma unroll
        for (int j = 0; j < 4; ++j) {
            float c = __uint_as_float(v[i][j]);
            cA += (c > thr_hi);
            cB += (c >= thr_lo) && (c <= thr_hi);
        }
    {
        int a = cA;
        #pragma unroll
        for (int off = 32; off; off >>= 1) a += __shfl_xor(a, off, 64);
        if ((tid & 63) == 0) wsum[tid >> 6] = a;
    }
    __syncthreads();
    const int nA = wsum[0] + wsum[1] + wsum[2] + wsum[3];
    __syncthreads();

    scan[tid] = cB;
    __syncthreads();
    #pragma unroll
    for (int off = 1; off < 256; off <<= 1) {
        int a = scan[tid];
        int b = (tid >= off) ? scan[tid - off] : 0;
        __syncthreads();
        scan[tid] = a + b;
        __syncthreads();
    }
    int posB = scan[tid] - cB;
    int nb   = scan[255];
    if (nb > MAXB) nb = MAXB;

    {
        int p = posB;
        #pragma unroll
        for (int i = 0; i < 16; ++i)
            #pragma unroll
            for (int j = 0; j < 4; ++j) {
                float c = __uint_as_float(v[i][j]);
                if ((c >= thr_lo) && (c <= thr_hi)) {
                    if (p < MAXB) bidx[p] = i * 1024 + tid * 4 + j;
                    ++p;
                }
            }
    }
    __syncthreads();

    // --- 3) exact f64 pre for band candidates
    const float* xrow = x + (size_t)row * D_IN;
    for (int jj = 0; jj < nb; ++jj) {
        int s = bidx[jj];
        const float* wrow = W_enc + (size_t)s * D_IN;
        double a = 0.0;
        #pragma unroll
        for (int q = 0; q < 8; ++q)
            a += (double)xrow[tid * 8 + q] * (double)wrow[tid * 8 + q];
        #pragma unroll
        for (int off = 32; off; off >>= 1) a += __shfl_xor(a, off, 64);
        if ((tid & 63) == 0) dsum[tid >> 6] = a;
        __syncthreads();
        if (tid == 0)
            exactv[jj] = dsum[0] + dsum[1] + dsum[2] + dsum[3]
                         + (double)b_enc[s] - (double)tau[s];
        __syncthreads();
    }

    int m = K - nA;
    if (m > nb) m = nb;
    if (tid < nb) {
        double e = exactv[tid];
        int rank = 0;
        for (int l = 0; l < nb; ++l) rank += (exactv[l] > e);
        selfl[tid] = (rank < m) ? 1 : 0;
    }
    __syncthreads();

    unsigned ov0 = 0u, ov1 = 0u;
    for (int jj = 0; jj < nb; ++jj) {
        int s = bidx[jj];
        if (((s >> 2) & 255) == tid && selfl[jj]) {
            int b = (s >> 10) * 4 + (s & 3);
            if (b < 32) ov0 |= 1u << b; else ov1 |= 1u << (b - 32);
        }
    }

    // --- 4) final keep predicate, compaction, writes
    int kc = 0;
    #pragma unroll
    for (int i = 0; i < 16; ++i)
        #pragma unroll
        for (int j = 0; j < 4; ++j) {
            float c = __uint_as_float(v[i][j]);
            int b = i * 4 + j;
            bool sel = (c > thr_hi) || ((b < 32 ? (ov0 >> b) : (ov1 >> (b - 32))) & 1);
            kc += sel && (c > 0.f);
        }
    __syncthreads();
    scan[tid] = kc;
    __syncthreads();
    #pragma unroll
    for (int off = 1; off < 256; off <<= 1) {
        int a = scan[tid];
        int b = (tid >= off) ? scan[tid - off] : 0;
        __syncthreads();
        scan[tid] = a + b;
        __syncthreads();
    }
    int pos   = scan[tid] - kc;
    int total = scan[255];

    #pragma unroll
    for (int i = 0; i < 16; ++i) {
        float4 cf; float4 mf;
        #pragma unroll
        for (int j = 0; j < 4; ++j) {
            float c = __uint_as_float(v[i][j]);
            int b = i * 4 + j;
            bool sel = (c > thr_hi) || ((b < 32 ? (ov0 >> b) : (ov1 >> (b - 32))) & 1);
            bool m_  = sel && (c > 0.f);
            float cv = sel ? c : 0.f;
            ((float*)&cf)[j] = cv;
            ((float*)&mf)[j] = m_ ? 1.f : 0.f;
            if (m_) {
                if (pos < CAP) {
                    idx_out[row * CAP + pos] = i * 1024 + tid * 4 + j;
                    val_out[row * CAP + pos] = cv;
                }
                ++pos;
            }
        }
        long o = base + i * 1024 + tid * 4;
        *(float4*)(codes + o) = cf;
        *(float4*)(mask  + o) = mf;
    }
    if (tid == 0) cnt_out[row] = total < CAP ? total : CAP;
}

// ---------------------------------------------------------------------------
// K4: recon[b,:] = sum_j val_j * W_decT[idx_j, :]
// ---------------------------------------------------------------------------
__global__ __launch_bounds__(256) void recon_sparse(const float* __restrict__ W_decT,
                                                    const int* __restrict__ cnt,
                                                    const int* __restrict__ idx,
                                                    const float* __restrict__ val,
                                                    float* __restrict__ recon) {
    const int row = blockIdx.x;
    const int tid = threadIdx.x;
    __shared__ int   s_idx[CAP];
    __shared__ float s_val[CAP];
    const int n = cnt[row];
    for (int j = tid; j < n; j += 256) {
        s_idx[j] = idx[row * CAP + j];
        s_val[j] = val[row * CAP + j];
    }
    __syncthreads();

    float4 a0 = {0.f, 0.f, 0.f, 0.f};
    float4 a1 = {0.f, 0.f, 0.f, 0.f};
    for (int j = 0; j < n; ++j) {
        float c = s_val[j];
        const float4* w = (const float4*)(W_decT + (long)s_idx[j] * D_IN);
        float4 w0 = w[tid];
        float4 w1 = w[tid + 256];
        a0.x = fmaf(c, w0.x, a0.x); a0.y = fmaf(c, w0.y, a0.y);
        a0.z = fmaf(c, w0.z, a0.z); a0.w = fmaf(c, w0.w, a0.w);
        a1.x = fmaf(c, w1.x, a1.x); a1.y = fmaf(c, w1.y, a1.y);
        a1.z = fmaf(c, w1.z, a1.z); a1.w = fmaf(c, w1.w, a1.w);
    }
    float4* out = (float4*)(recon + (long)row * D_IN);
    out[tid]       = a0;
    out[tid + 256] = a1;
}

// ---------------------------------------------------------------------------
// Workspace (peak ~136 MB), phase-overlapped:
//   phase A: [0,64M) w_f16 ; [64M,80M) x_f16
//   phase B: [0,128M) W_decT (overwrites f16 arrays) ; [128M,...) cnt/idx/val
// ---------------------------------------------------------------------------
extern "C" void kernel_launch(void* const* d_in, const int* in_sizes, int n_in,
                              void* d_out, int out_size, void* d_ws, size_t ws_size,
                              hipStream_t stream) {
    const float* x     = (const float*)d_in[0];
    const float* W_enc = (const float*)d_in[1];
    const float* b_enc = (const float*)d_in[2];
    const float* tau   = (const float*)d_in[3];
    const float* W_dec = (const float*)d_in[4];
    const int*   kptr  = (const int*)d_in[5];

    float* recon = (float*)d_out;
    float* codes = recon + (size_t)BATCH * D_IN;
    float* maskp = codes + (size_t)BATCH * D_SAE;

    char* w = (char*)d_ws;
    const size_t WDT = (size_t)D_SAE * D_IN * 4;        // 128 MB (W_decT, phase B)
    ushort* w_f16  = (ushort*)w;                        // [0, 64M)
    ushort* x_f16  = (ushort*)(w + (size_t)D_SAE * D_IN * 2);   // [64M, 80M)
    float*  W_decT = (float*)w;
    int*    cnt    = (int*)  (w + WDT);
    int*    idxl   = (int*)  (w + WDT + 16384);
    float*  vall   = (float*)(w + WDT + 16384 + (size_t)BATCH * CAP * 4);

    hipLaunchKernelGGL(to_f16, dim3(1024), dim3(256), 0, stream,
                       x, x_f16, BATCH * D_IN / 4);
    hipLaunchKernelGGL(to_f16, dim3(4096), dim3(256), 0, stream,
                       W_enc, w_f16, D_SAE * D_IN / 4);
    hipLaunchKernelGGL(gemm_enc_mfma, dim3(BATCH / 128, D_SAE / 128), dim3(256), 0, stream,
                       x_f16, w_f16, b_enc, tau, codes);
    hipLaunchKernelGGL(select_apply, dim3(BATCH), dim3(256), 0, stream,
                       codes, maskp, kptr, x, W_enc, b_enc, tau, cnt, idxl, vall);
    hipLaunchKernelGGL(transpose_wdec, dim3(D_SAE / 32, D_IN / 32), dim3(32, 8), 0, stream,
                       W_dec, W_decT);
    hipLaunchKernelGGL(recon_sparse, dim3(BATCH), dim3(256), 0, stream,
                       W_decT, cnt, idxl, vall, recon);
}

// Round 5
// 903.553 us; speedup vs baseline: 4.0322x; 1.1547x over previous
//
#include <hip/hip_runtime.h>

#define D_IN   2048
#define D_SAE  16384
#define BATCH  4096
#define CAP    256      // max compacted nonzeros per row
#define MAXB   64       // max boundary-band candidates per row
#define DELTA  6e-3f    // band half-width; >= 4x max f16-GEMM pre error
#define BWIDTH 2e-3f    // binary-search early-exit interval width

typedef __attribute__((ext_vector_type(8))) _Float16 f16x8;
typedef __attribute__((ext_vector_type(4))) _Float16 f16x4;
typedef __attribute__((ext_vector_type(4))) float f32x4;

// ---------------------------------------------------------------------------
// K0: convert f32 -> f16 (RN). Error <= 2^-11 relative.
// ---------------------------------------------------------------------------
__global__ __launch_bounds__(256) void to_f16(const float* __restrict__ in,
                                              ushort* __restrict__ out, int n4) {
    int i = blockIdx.x * blockDim.x + threadIdx.x;
    int stride = gridDim.x * blockDim.x;
    for (; i < n4; i += stride) {
        float4 v = ((const float4*)in)[i];
        ushort4 h;
        float*  vp = (float*)&v;
        ushort* hp = (ushort*)&h;
        #pragma unroll
        for (int j = 0; j < 4; ++j) {
            _Float16 f = (_Float16)vp[j];
            hp[j] = *(ushort*)&f;
        }
        ((ushort4*)out)[i] = h;
    }
}

// ---------------------------------------------------------------------------
// K1: codes[b][s] = relu( x·W_enc[s] + b_enc[s] - tau[s] ), f16 MFMA.
// 128x128 tile, BK=64 (32 KB LDS), 4 waves (64x64 each), 2-barrier K-loop,
// global_load_lds width-16 staging. 32 K-steps total.
// ---------------------------------------------------------------------------
__device__ __forceinline__ void async_copy16(const void* g, void* l) {
    __builtin_amdgcn_global_load_lds(
        (const __attribute__((address_space(1))) unsigned int*)g,
        (__attribute__((address_space(3))) unsigned int*)l, 16, 0, 0);
}

__global__ __launch_bounds__(256) void gemm_enc_mfma(
        const ushort* __restrict__ xh,    // x_f16 [4096][2048]
        const ushort* __restrict__ wh,    // w_f16 [16384][2048]
        const float* __restrict__ b_enc,
        const float* __restrict__ tau,
        float* __restrict__ codes) {
    __shared__ __align__(16) ushort lds[2][128][64];   // A, B = 32 KB
    const int tid  = threadIdx.x;
    const int wid  = tid >> 6;
    const int lane = tid & 63;
    const int m0 = blockIdx.x * 128;   // batch panel
    const int s0 = blockIdx.y * 128;   // feature panel
    const int wm = wid >> 1, wn = wid & 1;

    // staging: waves 0,1 -> A halves; waves 2,3 -> B halves. 8 loads/lane/step.
    const int arr  = wid >> 1;         // 0=A, 1=B
    const int half = wid & 1;          // row half
    const ushort* gsrc = (arr == 0) ? (xh + (size_t)m0 * D_IN)
                                    : (wh + (size_t)s0 * D_IN);
    // issue i: 8 rows (lane>>3), 16B chunks (lane&7)
    const ushort* gthread = gsrc + (size_t)(half * 64 + (lane >> 3)) * D_IN + (lane & 7) * 8;

    f32x4 acc[4][4] = {};

    const int fr = lane & 15;
    const int fk = (lane >> 4) * 8;

    for (int k0 = 0; k0 < D_IN; k0 += 64) {
        #pragma unroll
        for (int i = 0; i < 8; ++i)
            async_copy16(gthread + (size_t)i * 8 * D_IN + k0,
                         &lds[arr][half * 64 + i * 8][0]);
        __syncthreads();

        #pragma unroll
        for (int kk = 0; kk < 2; ++kk) {
            f16x8 a[4], b[4];
            #pragma unroll
            for (int f = 0; f < 4; ++f) {
                a[f] = *(const f16x8*)&lds[0][wm * 64 + f * 16 + fr][kk * 32 + fk];
                b[f] = *(const f16x8*)&lds[1][wn * 64 + f * 16 + fr][kk * 32 + fk];
            }
            #pragma unroll
            for (int i = 0; i < 4; ++i)
                #pragma unroll
                for (int j = 0; j < 4; ++j)
                    acc[i][j] = __builtin_amdgcn_mfma_f32_16x16x32_f16(a[i], b[j], acc[i][j], 0, 0, 0);
        }
        __syncthreads();
    }

    // epilogue: + b_enc - tau, relu; C/D layout col=lane&15, row=(lane>>4)*4+reg
    const int fq = lane >> 4;
    #pragma unroll
    for (int j = 0; j < 4; ++j) {
        int col = s0 + wn * 64 + j * 16 + fr;
        float be = b_enc[col] - tau[col];
        #pragma unroll
        for (int i = 0; i < 4; ++i) {
            int rbase = m0 + wm * 64 + i * 16 + fq * 4;
            #pragma unroll
            for (int r = 0; r < 4; ++r) {
                float v = fmaxf(acc[i][j][r] + be, 0.f);
                codes[(size_t)(rbase + r) * D_SAE + col] = v;
            }
        }
    }
}

// ---------------------------------------------------------------------------
// K2: transpose W_dec (f32 [2048][16384]) -> W_decT (f16 [16384][2048])
// 64x64 tiles, 256 threads.
// ---------------------------------------------------------------------------
__global__ __launch_bounds__(256) void transpose_wdec_f16(const float* __restrict__ W_dec,
                                                          _Float16* __restrict__ W_decT) {
    __shared__ float t[64][65];
    const int tid = threadIdx.x;
    const int x0 = blockIdx.x * 64;   // feature (s)
    const int y0 = blockIdx.y * 64;   // d_in (i)
    const int tx = tid & 15;
    const int ty = tid >> 4;
    #pragma unroll
    for (int p = 0; p < 4; ++p) {
        float4 v = *(const float4*)&W_dec[(size_t)(y0 + p * 16 + ty) * D_SAE + x0 + tx * 4];
        t[p * 16 + ty][tx * 4 + 0] = v.x;
        t[p * 16 + ty][tx * 4 + 1] = v.y;
        t[p * 16 + ty][tx * 4 + 2] = v.z;
        t[p * 16 + ty][tx * 4 + 3] = v.w;
    }
    __syncthreads();
    #pragma unroll
    for (int p = 0; p < 4; ++p) {
        int s = p * 16 + ty;
        f16x4 o;
        #pragma unroll
        for (int q = 0; q < 4; ++q)
            o[q] = (_Float16)t[tx * 4 + q][s];
        *(f16x4*)&W_decT[(size_t)(x0 + s) * D_IN + y0 + tx * 4] = o;
    }
}

// ---------------------------------------------------------------------------
// K3: exact rank-K select with f64 band refinement. Early-exit binary search:
// localize kth to [f(lo), f(hi)] with f(hi)-f(lo) <= BWIDTH, band covers
// [f(lo)-DELTA, f(hi)+DELTA] (DELTA >= 4x max pre error -> selection exact).
// ---------------------------------------------------------------------------
__global__ __launch_bounds__(256) void select_apply(
        float* __restrict__ codes, float* __restrict__ mask,
        const int* __restrict__ kptr,
        const float* __restrict__ x, const float* __restrict__ W_enc,
        const float* __restrict__ b_enc, const float* __restrict__ tau,
        int* __restrict__ cnt_out, int* __restrict__ idx_out,
        float* __restrict__ val_out) {
    const int row = blockIdx.x;
    const int tid = threadIdx.x;
    const long base = (long)row * D_SAE;

    unsigned v[16][4];
    #pragma unroll
    for (int i = 0; i < 16; ++i) {
        uint4 u = *(const uint4*)(codes + base + i * 1024 + tid * 4);
        v[i][0] = u.x; v[i][1] = u.y; v[i][2] = u.z; v[i][3] = u.w;
    }

    int K = kptr[0];
    if (K > D_SAE) K = D_SAE;

    __shared__ int    wsum[4];
    __shared__ int    scan[256];
    __shared__ int    bidx[MAXB];
    __shared__ double exactv[MAXB];
    __shared__ int    selfl[MAXB];
    __shared__ double dsum[4];

    // --- 1) early-exit binary search on bit patterns
    unsigned lo = 0u, hi = 0x7F800000u;
    while (hi - lo > 1u &&
           __uint_as_float(hi) - __uint_as_float(lo) > BWIDTH) {
        unsigned mid = lo + ((hi - lo) >> 1);
        int c = 0;
        #pragma unroll
        for (int i = 0; i < 16; ++i)
            #pragma unroll
            for (int j = 0; j < 4; ++j)
                c += (v[i][j] >= mid);
        #pragma unroll
        for (int off = 32; off; off >>= 1) c += __shfl_xor(c, off, 64);
        if ((tid & 63) == 0) wsum[tid >> 6] = c;
        __syncthreads();
        int tot = wsum[0] + wsum[1] + wsum[2] + wsum[3];
        __syncthreads();
        if (tot >= K) lo = mid; else hi = mid;
    }
    const float thr_hi = __uint_as_float(hi) + DELTA;
    const float thr_lo = __uint_as_float(lo) - DELTA;

    // --- 2) count above / collect band
    int cA = 0, cB = 0;
    #pragma unroll
    for (int i = 0; i < 16; ++i)
        #pragma unroll
        for (int j = 0; j < 4; ++j) {
            float c = __uint_as_float(v[i][j]);
            cA += (c > thr_hi);
            cB += (c >= thr_lo) && (c <= thr_hi);
        }
    {
        int a = cA;
        #pragma unroll
        for (int off = 32; off; off >>= 1) a += __shfl_xor(a, off, 64);
        if ((tid & 63) == 0) wsum[tid >> 6] = a;
    }
    __syncthreads();
    const int nA = wsum[0] + wsum[1] + wsum[2] + wsum[3];
    __syncthreads();

    scan[tid] = cB;
    __syncthreads();
    #pragma unroll
    for (int off = 1; off < 256; off <<= 1) {
        int a = scan[tid];
        int b = (tid >= off) ? scan[tid - off] : 0;
        __syncthreads();
        scan[tid] = a + b;
        __syncthreads();
    }
    int posB = scan[tid] - cB;
    int nb   = scan[255];
    if (nb > MAXB) nb = MAXB;

    {
        int p = posB;
        #pragma unroll
        for (int i = 0; i < 16; ++i)
            #pragma unroll
            for (int j = 0; j < 4; ++j) {
                float c = __uint_as_float(v[i][j]);
                if ((c >= thr_lo) && (c <= thr_hi)) {
                    if (p < MAXB) bidx[p] = i * 1024 + tid * 4 + j;
                    ++p;
                }
            }
    }
    __syncthreads();

    // --- 3) exact f64 pre for band candidates
    const float* xrow = x + (size_t)row * D_IN;
    for (int jj = 0; jj < nb; ++jj) {
        int s = bidx[jj];
        const float* wrow = W_enc + (size_t)s * D_IN;
        double a = 0.0;
        #pragma unroll
        for (int q = 0; q < 8; ++q)
            a += (double)xrow[tid * 8 + q] * (double)wrow[tid * 8 + q];
        #pragma unroll
        for (int off = 32; off; off >>= 1) a += __shfl_xor(a, off, 64);
        if ((tid & 63) == 0) dsum[tid >> 6] = a;
        __syncthreads();
        if (tid == 0)
            exactv[jj] = dsum[0] + dsum[1] + dsum[2] + dsum[3]
                         + (double)b_enc[s] - (double)tau[s];
        __syncthreads();
    }

    int m = K - nA;
    if (m > nb) m = nb;
    if (tid < nb) {
        double e = exactv[tid];
        int rank = 0;
        for (int l = 0; l < nb; ++l) rank += (exactv[l] > e);
        selfl[tid] = (rank < m) ? 1 : 0;
    }
    __syncthreads();

    unsigned ov0 = 0u, ov1 = 0u;
    for (int jj = 0; jj < nb; ++jj) {
        int s = bidx[jj];
        if (((s >> 2) & 255) == tid && selfl[jj]) {
            int b = (s >> 10) * 4 + (s & 3);
            if (b < 32) ov0 |= 1u << b; else ov1 |= 1u << (b - 32);
        }
    }

    // --- 4) final keep predicate, compaction, writes
    int kc = 0;
    #pragma unroll
    for (int i = 0; i < 16; ++i)
        #pragma unroll
        for (int j = 0; j < 4; ++j) {
            float c = __uint_as_float(v[i][j]);
            int b = i * 4 + j;
            bool sel = (c > thr_hi) || ((b < 32 ? (ov0 >> b) : (ov1 >> (b - 32))) & 1);
            kc += sel && (c > 0.f);
        }
    __syncthreads();
    scan[tid] = kc;
    __syncthreads();
    #pragma unroll
    for (int off = 1; off < 256; off <<= 1) {
        int a = scan[tid];
        int b = (tid >= off) ? scan[tid - off] : 0;
        __syncthreads();
        scan[tid] = a + b;
        __syncthreads();
    }
    int pos   = scan[tid] - kc;
    int total = scan[255];

    #pragma unroll
    for (int i = 0; i < 16; ++i) {
        float4 cf; float4 mf;
        #pragma unroll
        for (int j = 0; j < 4; ++j) {
            float c = __uint_as_float(v[i][j]);
            int b = i * 4 + j;
            bool sel = (c > thr_hi) || ((b < 32 ? (ov0 >> b) : (ov1 >> (b - 32))) & 1);
            bool m_  = sel && (c > 0.f);
            float cv = sel ? c : 0.f;
            ((float*)&cf)[j] = cv;
            ((float*)&mf)[j] = m_ ? 1.f : 0.f;
            if (m_) {
                if (pos < CAP) {
                    idx_out[row * CAP + pos] = i * 1024 + tid * 4 + j;
                    val_out[row * CAP + pos] = cv;
                }
                ++pos;
            }
        }
        long o = base + i * 1024 + tid * 4;
        *(float4*)(codes + o) = cf;
        *(float4*)(mask  + o) = mf;
    }
    if (tid == 0) cnt_out[row] = total < CAP ? total : CAP;
}

// ---------------------------------------------------------------------------
// K4: recon[b,:] = sum_j val_j * W_decT16[idx_j, :]   (f16 gather, f32 accum)
// thread owns cols [tid*4, tid*4+4) and [1024+tid*4, +4): 8B loads, 16B stores
// ---------------------------------------------------------------------------
__global__ __launch_bounds__(256) void recon_sparse(const _Float16* __restrict__ Wd16,
                                                    const int* __restrict__ cnt,
                                                    const int* __restrict__ idx,
                                                    const float* __restrict__ val,
                                                    float* __restrict__ recon) {
    const int row = blockIdx.x;
    const int tid = threadIdx.x;
    __shared__ int   s_idx[CAP];
    __shared__ float s_val[CAP];
    const int n = cnt[row];
    for (int j = tid; j < n; j += 256) {
        s_idx[j] = idx[row * CAP + j];
        s_val[j] = val[row * CAP + j];
    }
    __syncthreads();

    float4 a0 = {0.f, 0.f, 0.f, 0.f};
    float4 a1 = {0.f, 0.f, 0.f, 0.f};
    for (int j = 0; j < n; ++j) {
        float c = s_val[j];
        const _Float16* w = Wd16 + (size_t)s_idx[j] * D_IN;
        f16x4 w0 = *(const f16x4*)(w + tid * 4);
        f16x4 w1 = *(const f16x4*)(w + 1024 + tid * 4);
        a0.x = fmaf(c, (float)w0[0], a0.x); a0.y = fmaf(c, (float)w0[1], a0.y);
        a0.z = fmaf(c, (float)w0[2], a0.z); a0.w = fmaf(c, (float)w0[3], a0.w);
        a1.x = fmaf(c, (float)w1[0], a1.x); a1.y = fmaf(c, (float)w1[1], a1.y);
        a1.z = fmaf(c, (float)w1[2], a1.z); a1.w = fmaf(c, (float)w1[3], a1.w);
    }
    float* out = recon + (size_t)row * D_IN;
    *(float4*)(out + tid * 4)        = a0;
    *(float4*)(out + 1024 + tid * 4) = a1;
}

// ---------------------------------------------------------------------------
// Workspace (peak ~152.4 MB):
//   [0,64M)    w_f16
//   [64M,80M)  x_f16
//   [80M,144M) W_decT f16        (written after gemm, no overlap conflict)
//   [144M,..)  cnt (16K), idx (4M), val (4M)
// ---------------------------------------------------------------------------
extern "C" void kernel_launch(void* const* d_in, const int* in_sizes, int n_in,
                              void* d_out, int out_size, void* d_ws, size_t ws_size,
                              hipStream_t stream) {
    const float* x     = (const float*)d_in[0];
    const float* W_enc = (const float*)d_in[1];
    const float* b_enc = (const float*)d_in[2];
    const float* tau   = (const float*)d_in[3];
    const float* W_dec = (const float*)d_in[4];
    const int*   kptr  = (const int*)d_in[5];

    float* recon = (float*)d_out;
    float* codes = recon + (size_t)BATCH * D_IN;
    float* maskp = codes + (size_t)BATCH * D_SAE;

    char* w = (char*)d_ws;
    const size_t OFF_X   = (size_t)D_SAE * D_IN * 2;            // 64M
    const size_t OFF_WDT = OFF_X + (size_t)BATCH * D_IN * 2;    // 80M
    const size_t OFF_CNT = OFF_WDT + (size_t)D_SAE * D_IN * 2;  // 144M
    ushort*   w_f16  = (ushort*)w;
    ushort*   x_f16  = (ushort*)(w + OFF_X);
    _Float16* W_decT = (_Float16*)(w + OFF_WDT);
    int*      cnt    = (int*)  (w + OFF_CNT);
    int*      idxl   = (int*)  (w + OFF_CNT + 16384);
    float*    vall   = (float*)(w + OFF_CNT + 16384 + (size_t)BATCH * CAP * 4);

    hipLaunchKernelGGL(to_f16, dim3(1024), dim3(256), 0, stream,
                       x, x_f16, BATCH * D_IN / 4);
    hipLaunchKernelGGL(to_f16, dim3(4096), dim3(256), 0, stream,
                       W_enc, w_f16, D_SAE * D_IN / 4);
    hipLaunchKernelGGL(gemm_enc_mfma, dim3(BATCH / 128, D_SAE / 128), dim3(256), 0, stream,
                       x_f16, w_f16, b_enc, tau, codes);
    hipLaunchKernelGGL(select_apply, dim3(BATCH), dim3(256), 0, stream,
                       codes, maskp, kptr, x, W_enc, b_enc, tau, cnt, idxl, vall);
    hipLaunchKernelGGL(transpose_wdec_f16, dim3(D_SAE / 64, D_IN / 64), dim3(256), 0, stream,
                       W_dec, W_decT);
    hipLaunchKernelGGL(recon_sparse, dim3(BATCH), dim3(256), 0, stream,
                       W_decT, cnt, idxl, vall, recon);
}

// Round 6
// 852.975 us; speedup vs baseline: 4.2713x; 1.0593x over previous
//
#include <hip/hip_runtime.h>

#define D_IN   2048
#define D_SAE  16384
#define BATCH  4096
#define CAP    256      // max compacted nonzeros per row
#define MAXB   64       // max boundary-band candidates per row
#define DELTA  1e-2f    // band half-width; >= 2x (gemm f16 err + f16 storage err)

typedef __attribute__((ext_vector_type(8))) _Float16 f16x8;
typedef __attribute__((ext_vector_type(4))) _Float16 f16x4;
typedef __attribute__((ext_vector_type(4))) float f32x4;

// ---------------------------------------------------------------------------
// K0: convert f32 -> f16 (RN).
// ---------------------------------------------------------------------------
__global__ __launch_bounds__(256) void to_f16(const float* __restrict__ in,
                                              ushort* __restrict__ out, int n4) {
    int i = blockIdx.x * blockDim.x + threadIdx.x;
    int stride = gridDim.x * blockDim.x;
    for (; i < n4; i += stride) {
        float4 v = ((const float4*)in)[i];
        ushort4 h;
        float*  vp = (float*)&v;
        ushort* hp = (ushort*)&h;
        #pragma unroll
        for (int j = 0; j < 4; ++j) {
            _Float16 f = (_Float16)vp[j];
            hp[j] = *(ushort*)&f;
        }
        ((ushort4*)out)[i] = h;
    }
}

// ---------------------------------------------------------------------------
// K1: raw[b][s] = relu( x·W_enc[s] + b_enc[s] - tau[s] ), f16 MFMA.
// Round-4 verified structure: 128x128 tile, BK=32, 16 KB LDS, 4 waves,
// global_load_lds width-16, 2-barrier K-loop. Output f16 or f32 (template).
// ---------------------------------------------------------------------------
__device__ __forceinline__ void async_copy16(const void* g, void* l) {
    __builtin_amdgcn_global_load_lds(
        (const __attribute__((address_space(1))) unsigned int*)g,
        (__attribute__((address_space(3))) unsigned int*)l, 16, 0, 0);
}

template<int F16OUT>
__global__ __launch_bounds__(256) void gemm_enc_mfma(
        const ushort* __restrict__ xh,    // x_f16 [4096][2048]
        const ushort* __restrict__ wh,    // w_f16 [16384][2048]
        const float* __restrict__ b_enc,
        const float* __restrict__ tau,
        void* __restrict__ rawout) {
    __shared__ __align__(16) ushort lds[2][128][32];   // A, B = 16 KB
    const int tid  = threadIdx.x;
    const int wid  = tid >> 6;
    const int lane = tid & 63;
    const int m0 = blockIdx.x * 128;   // batch panel
    const int s0 = blockIdx.y * 128;   // feature panel
    const int wm = wid >> 1, wn = wid & 1;

    const int arr  = wid >> 1;         // 0=A, 1=B
    const int half = wid & 1;          // row half
    const ushort* gsrc = (arr == 0) ? (xh + (size_t)m0 * D_IN)
                                    : (wh + (size_t)s0 * D_IN);
    const ushort* gthread = gsrc + (size_t)(half * 64 + (lane >> 2)) * D_IN + (lane & 3) * 8;

    f32x4 acc[4][4] = {};

    const int fr = lane & 15;
    const int fk = (lane >> 4) * 8;

    for (int k0 = 0; k0 < D_IN; k0 += 32) {
        #pragma unroll
        for (int i = 0; i < 4; ++i)
            async_copy16(gthread + (size_t)i * 16 * D_IN + k0,
                         &lds[arr][half * 64 + i * 16][0]);
        __syncthreads();

        f16x8 a[4], b[4];
        #pragma unroll
        for (int f = 0; f < 4; ++f) {
            a[f] = *(const f16x8*)&lds[0][wm * 64 + f * 16 + fr][fk];
            b[f] = *(const f16x8*)&lds[1][wn * 64 + f * 16 + fr][fk];
        }
        #pragma unroll
        for (int i = 0; i < 4; ++i)
            #pragma unroll
            for (int j = 0; j < 4; ++j)
                acc[i][j] = __builtin_amdgcn_mfma_f32_16x16x32_f16(a[i], b[j], acc[i][j], 0, 0, 0);
        __syncthreads();
    }

    // epilogue: + b_enc - tau, relu; C/D layout col=lane&15, row=(lane>>4)*4+reg
    const int fq = lane >> 4;
    #pragma unroll
    for (int j = 0; j < 4; ++j) {
        int col = s0 + wn * 64 + j * 16 + fr;
        float be = b_enc[col] - tau[col];
        #pragma unroll
        for (int i = 0; i < 4; ++i) {
            int rbase = m0 + wm * 64 + i * 16 + fq * 4;
            #pragma unroll
            for (int r = 0; r < 4; ++r) {
                float v = fmaxf(acc[i][j][r] + be, 0.f);
                size_t ofs = (size_t)(rbase + r) * D_SAE + col;
                if (F16OUT) {
                    _Float16 hv = (_Float16)v;
                    __builtin_nontemporal_store(*(ushort*)&hv, (ushort*)rawout + ofs);
                } else {
                    __builtin_nontemporal_store(v, (float*)rawout + ofs);
                }
            }
        }
    }
}

// ---------------------------------------------------------------------------
// K2: transpose W_dec (f32 [2048][16384]) -> W_decT (f16 [16384][2048])
// ---------------------------------------------------------------------------
__global__ __launch_bounds__(256) void transpose_wdec_f16(const float* __restrict__ W_dec,
                                                          _Float16* __restrict__ W_decT) {
    __shared__ float t[64][65];
    const int tid = threadIdx.x;
    const int x0 = blockIdx.x * 64;   // feature (s)
    const int y0 = blockIdx.y * 64;   // d_in (i)
    const int tx = tid & 15;
    const int ty = tid >> 4;
    #pragma unroll
    for (int p = 0; p < 4; ++p) {
        float4 v = *(const float4*)&W_dec[(size_t)(y0 + p * 16 + ty) * D_SAE + x0 + tx * 4];
        t[p * 16 + ty][tx * 4 + 0] = v.x;
        t[p * 16 + ty][tx * 4 + 1] = v.y;
        t[p * 16 + ty][tx * 4 + 2] = v.z;
        t[p * 16 + ty][tx * 4 + 3] = v.w;
    }
    __syncthreads();
    #pragma unroll
    for (int p = 0; p < 4; ++p) {
        int s = p * 16 + ty;
        f16x4 o;
        #pragma unroll
        for (int q = 0; q < 4; ++q)
            o[q] = (_Float16)t[tx * 4 + q][s];
        *(f16x4*)&W_decT[(size_t)(x0 + s) * D_IN + y0 + tx * 4] = o;
    }
}

// ---------------------------------------------------------------------------
// K3: exact rank-K select. Histogram-based kth localization (2 passes over
// f16 bit patterns, monotone for non-negative values), then f64 band
// refinement (exact when DELTA >= 2 * max approx error). Element layout:
// s = i*2048 + tid*8 + j, i<8, j<8.
// ---------------------------------------------------------------------------
template<int SRC16>
__global__ __launch_bounds__(256) void select_apply(
        const void* __restrict__ rawsrc,
        float* __restrict__ codes, float* __restrict__ mask,
        const int* __restrict__ kptr,
        const float* __restrict__ x, const float* __restrict__ W_enc,
        const float* __restrict__ b_enc, const float* __restrict__ tau,
        int* __restrict__ cnt_out, int* __restrict__ idx_out,
        float* __restrict__ val_out) {
    const int row = blockIdx.x;
    const int tid = threadIdx.x;
    const long base = (long)row * D_SAE;

    float c[8][8];
    if (SRC16) {
        const ushort* rh = (const ushort*)rawsrc;
        #pragma unroll
        for (int i = 0; i < 8; ++i) {
            uint4 u = *(const uint4*)(rh + base + i * 2048 + tid * 8);
            const unsigned* up = (const unsigned*)&u;
            #pragma unroll
            for (int q = 0; q < 4; ++q) {
                ushort b0 = (ushort)(up[q] & 0xFFFFu), b1 = (ushort)(up[q] >> 16);
                _Float16 h0, h1;
                *(ushort*)&h0 = b0; *(ushort*)&h1 = b1;
                c[i][2 * q]     = (float)h0;
                c[i][2 * q + 1] = (float)h1;
            }
        }
    } else {
        const float* rf = (const float*)rawsrc;
        #pragma unroll
        for (int i = 0; i < 8; ++i) {
            float4 v0 = *(const float4*)(rf + base + i * 2048 + tid * 8);
            float4 v1 = *(const float4*)(rf + base + i * 2048 + tid * 8 + 4);
            c[i][0] = v0.x; c[i][1] = v0.y; c[i][2] = v0.z; c[i][3] = v0.w;
            c[i][4] = v1.x; c[i][5] = v1.y; c[i][6] = v1.z; c[i][7] = v1.w;
        }
    }

    int K = kptr[0];
    if (K > D_SAE) K = D_SAE;

    __shared__ int    hist[1024];
    __shared__ int    scan[256];
    __shared__ int    wsum[4];
    __shared__ int    bidx[MAXB];
    __shared__ double exactv[MAXB];
    __shared__ int    selfl[MAXB];
    __shared__ double dsum[4];
    __shared__ int    sh_B, sh_nAB, sh_kpat;

    // --- 1a) histogram of f16-pattern top-10 bits (1024 buckets)
    #pragma unroll
    for (int q = 0; q < 4; ++q) hist[tid + q * 256] = 0;
    if (tid == 0) { sh_B = -1; sh_nAB = 0; }
    __syncthreads();
    #pragma unroll
    for (int i = 0; i < 8; ++i)
        #pragma unroll
        for (int j = 0; j < 8; ++j) {
            _Float16 h = (_Float16)c[i][j];
            ushort pat = *(ushort*)&h;
            if (pat) atomicAdd(&hist[pat >> 6], 1);
        }
    __syncthreads();

    // --- 1b) suffix scan over buckets (thread tid owns buckets 4t..4t+3)
    int s_loc = hist[4 * tid] + hist[4 * tid + 1] + hist[4 * tid + 2] + hist[4 * tid + 3];
    const int my = 255 - tid;
    scan[my] = s_loc;
    __syncthreads();
    #pragma unroll
    for (int off = 1; off < 256; off <<= 1) {
        int a = scan[my];
        int b = (my >= off) ? scan[my - off] : 0;
        __syncthreads();
        scan[my] = a + b;
        __syncthreads();
    }
    int I = scan[my];        // count of elements in buckets >= 4*tid
    int E = I - s_loc;       // count in buckets >= 4*(tid+1)
    if (I >= K && E < K) {   // exactly one thread (when enough positives)
        int cnt = E, b;
        for (b = 4 * tid + 3; b > 4 * tid; --b) {
            cnt += hist[b];
            if (cnt >= K) break;
        }
        if (cnt < K) { cnt += hist[4 * tid]; b = 4 * tid; }
        sh_B = b;
        sh_nAB = cnt - hist[b];    // elements strictly above bucket B
    }
    __syncthreads();
    const int B = sh_B, nAB = sh_nAB;

    // --- 1c) second pass within bucket B (low 6 bits)
    if (tid < 64) hist[tid] = 0;
    __syncthreads();
    if (B >= 0) {
        #pragma unroll
        for (int i = 0; i < 8; ++i)
            #pragma unroll
            for (int j = 0; j < 8; ++j) {
                _Float16 h = (_Float16)c[i][j];
                ushort pat = *(ushort*)&h;
                if (pat && (int)(pat >> 6) == B) atomicAdd(&hist[pat & 63], 1);
            }
    }
    __syncthreads();
    if (tid == 0) {
        int kpat = 0;
        if (B >= 0) {
            int cnt = nAB, l;
            for (l = 63; l >= 0; --l) {
                cnt += hist[l];
                if (cnt >= K) break;
            }
            if (l < 0) l = 0;
            kpat = (B << 6) | l;
        }
        sh_kpat = kpat;
    }
    __syncthreads();
    _Float16 kh; *(ushort*)&kh = (ushort)sh_kpat;
    const float kf = (float)kh;
    const float thr_hi = kf + DELTA;
    const float thr_lo = kf - DELTA;

    // --- 2) count above / collect band
    int cA = 0, cB2 = 0;
    #pragma unroll
    for (int i = 0; i < 8; ++i)
        #pragma unroll
        for (int j = 0; j < 8; ++j) {
            float cc = c[i][j];
            cA  += (cc > thr_hi);
            cB2 += (cc >= thr_lo) && (cc <= thr_hi);
        }
    {
        int a = cA;
        #pragma unroll
        for (int off = 32; off; off >>= 1) a += __shfl_xor(a, off, 64);
        if ((tid & 63) == 0) wsum[tid >> 6] = a;
    }
    __syncthreads();
    const int nA = wsum[0] + wsum[1] + wsum[2] + wsum[3];
    __syncthreads();

    scan[tid] = cB2;
    __syncthreads();
    #pragma unroll
    for (int off = 1; off < 256; off <<= 1) {
        int a = scan[tid];
        int b = (tid >= off) ? scan[tid - off] : 0;
        __syncthreads();
        scan[tid] = a + b;
        __syncthreads();
    }
    int posB = scan[tid] - cB2;
    int nb   = scan[255];
    if (nb > MAXB) nb = MAXB;

    {
        int p = posB;
        #pragma unroll
        for (int i = 0; i < 8; ++i)
            #pragma unroll
            for (int j = 0; j < 8; ++j) {
                float cc = c[i][j];
                if ((cc >= thr_lo) && (cc <= thr_hi)) {
                    if (p < MAXB) bidx[p] = i * 2048 + tid * 8 + j;
                    ++p;
                }
            }
    }
    __syncthreads();

    // --- 3) exact f64 pre for band candidates
    const float* xrow = x + (size_t)row * D_IN;
    for (int jj = 0; jj < nb; ++jj) {
        int s = bidx[jj];
        const float* wrow = W_enc + (size_t)s * D_IN;
        double a = 0.0;
        #pragma unroll
        for (int q = 0; q < 8; ++q)
            a += (double)xrow[tid * 8 + q] * (double)wrow[tid * 8 + q];
        #pragma unroll
        for (int off = 32; off; off >>= 1) a += __shfl_xor(a, off, 64);
        if ((tid & 63) == 0) dsum[tid >> 6] = a;
        __syncthreads();
        if (tid == 0)
            exactv[jj] = dsum[0] + dsum[1] + dsum[2] + dsum[3]
                         + (double)b_enc[s] - (double)tau[s];
        __syncthreads();
    }

    int m = K - nA;
    if (m > nb) m = nb;
    if (tid < nb) {
        double e = exactv[tid];
        int rank = 0;
        for (int l = 0; l < nb; ++l) rank += (exactv[l] > e);
        selfl[tid] = (rank < m) ? 1 : 0;
    }
    __syncthreads();

    // per-thread override bits: owner tid = (s>>3)&255, bit = (s>>11)*8 + (s&7)
    unsigned long long ov = 0ull;
    for (int jj = 0; jj < nb; ++jj) {
        int s = bidx[jj];
        if (((s >> 3) & 255) == tid && selfl[jj])
            ov |= 1ull << (((s >> 11) << 3) | (s & 7));
    }

    // --- 4) final keep predicate, compaction, writes
    int kc = 0;
    #pragma unroll
    for (int i = 0; i < 8; ++i)
        #pragma unroll
        for (int j = 0; j < 8; ++j) {
            float cc = c[i][j];
            bool sel = (cc > thr_hi) || ((ov >> (i * 8 + j)) & 1ull);
            kc += sel && (cc > 0.f);
        }
    __syncthreads();
    scan[tid] = kc;
    __syncthreads();
    #pragma unroll
    for (int off = 1; off < 256; off <<= 1) {
        int a = scan[tid];
        int b = (tid >= off) ? scan[tid - off] : 0;
        __syncthreads();
        scan[tid] = a + b;
        __syncthreads();
    }
    int pos   = scan[tid] - kc;
    int total = scan[255];

    #pragma unroll
    for (int i = 0; i < 8; ++i) {
        f32x4 cf0, cf1, mf0, mf1;
        #pragma unroll
        for (int j = 0; j < 8; ++j) {
            float cc = c[i][j];
            bool sel = (cc > thr_hi) || ((ov >> (i * 8 + j)) & 1ull);
            bool m_  = sel && (cc > 0.f);
            float cv = sel ? cc : 0.f;
            float mv = m_ ? 1.f : 0.f;
            if (j < 4) { cf0[j] = cv; mf0[j] = mv; }
            else       { cf1[j - 4] = cv; mf1[j - 4] = mv; }
            if (m_) {
                if (pos < CAP) {
                    idx_out[row * CAP + pos] = i * 2048 + tid * 8 + j;
                    val_out[row * CAP + pos] = cv;
                }
                ++pos;
            }
        }
        long o = base + i * 2048 + tid * 8;
        __builtin_nontemporal_store(cf0, (f32x4*)(codes + o));
        __builtin_nontemporal_store(cf1, (f32x4*)(codes + o + 4));
        __builtin_nontemporal_store(mf0, (f32x4*)(mask + o));
        __builtin_nontemporal_store(mf1, (f32x4*)(mask + o + 4));
    }
    if (tid == 0) cnt_out[row] = total < CAP ? total : CAP;
}

// ---------------------------------------------------------------------------
// K4: recon[b,:] = sum_j val_j * W_decT16[idx_j, :]   (f16 gather, f32 accum)
// ---------------------------------------------------------------------------
__global__ __launch_bounds__(256) void recon_sparse(const _Float16* __restrict__ Wd16,
                                                    const int* __restrict__ cnt,
                                                    const int* __restrict__ idx,
                                                    const float* __restrict__ val,
                                                    float* __restrict__ recon) {
    const int row = blockIdx.x;
    const int tid = threadIdx.x;
    __shared__ int   s_idx[CAP];
    __shared__ float s_val[CAP];
    const int n = cnt[row];
    for (int j = tid; j < n; j += 256) {
        s_idx[j] = idx[row * CAP + j];
        s_val[j] = val[row * CAP + j];
    }
    __syncthreads();

    float4 a0 = {0.f, 0.f, 0.f, 0.f};
    float4 a1 = {0.f, 0.f, 0.f, 0.f};
    for (int j = 0; j < n; ++j) {
        float c = s_val[j];
        const _Float16* w = Wd16 + (size_t)s_idx[j] * D_IN;
        f16x4 w0 = *(const f16x4*)(w + tid * 4);
        f16x4 w1 = *(const f16x4*)(w + 1024 + tid * 4);
        a0.x = fmaf(c, (float)w0[0], a0.x); a0.y = fmaf(c, (float)w0[1], a0.y);
        a0.z = fmaf(c, (float)w0[2], a0.z); a0.w = fmaf(c, (float)w0[3], a0.w);
        a1.x = fmaf(c, (float)w1[0], a1.x); a1.y = fmaf(c, (float)w1[1], a1.y);
        a1.z = fmaf(c, (float)w1[2], a1.z); a1.w = fmaf(c, (float)w1[3], a1.w);
    }
    float* out = recon + (size_t)row * D_IN;
    *(float4*)(out + tid * 4)        = a0;
    *(float4*)(out + 1024 + tid * 4) = a1;
}

// ---------------------------------------------------------------------------
// Workspace:
//  f16-raw path (needs ~216.3 MB):
//   [0,64M)    w_f16 (phase A) / W_decT f16 (phase B, after select)
//   [64M,80M)  x_f16
//   [80M,208M) raw f16 codes
//   [208M,..)  cnt (16K), idx (4M), val (4M)
//  fallback (ws too small, ~88.3 MB): raw f32 lives in d_out codes region,
//   cnt/idx/val at 80M (round-5 flow).
// ---------------------------------------------------------------------------
extern "C" void kernel_launch(void* const* d_in, const int* in_sizes, int n_in,
                              void* d_out, int out_size, void* d_ws, size_t ws_size,
                              hipStream_t stream) {
    const float* x     = (const float*)d_in[0];
    const float* W_enc = (const float*)d_in[1];
    const float* b_enc = (const float*)d_in[2];
    const float* tau   = (const float*)d_in[3];
    const float* W_dec = (const float*)d_in[4];
    const int*   kptr  = (const int*)d_in[5];

    float* recon = (float*)d_out;
    float* codes = recon + (size_t)BATCH * D_IN;
    float* maskp = codes + (size_t)BATCH * D_SAE;

    char* w = (char*)d_ws;
    const size_t OFF_X   = (size_t)D_SAE * D_IN * 2;             // 64M
    const size_t OFF_RAW = OFF_X + (size_t)BATCH * D_IN * 2;     // 80M
    const size_t RAWSZ   = (size_t)BATCH * D_SAE * 2;            // 128M
    const size_t TAILSZ  = 16384 + 2 * (size_t)BATCH * CAP * 4;  // cnt+idx+val
    const bool f16raw = ws_size >= OFF_RAW + RAWSZ + TAILSZ;

    const size_t OFF_CNT = f16raw ? (OFF_RAW + RAWSZ) : OFF_RAW;
    ushort*   w_f16  = (ushort*)w;
    ushort*   x_f16  = (ushort*)(w + OFF_X);
    _Float16* W_decT = (_Float16*)w;                             // phase B
    int*      cnt    = (int*)  (w + OFF_CNT);
    int*      idxl   = (int*)  (w + OFF_CNT + 16384);
    float*    vall   = (float*)(w + OFF_CNT + 16384 + (size_t)BATCH * CAP * 4);
    void*     raw    = f16raw ? (void*)(w + OFF_RAW) : (void*)codes;

    hipLaunchKernelGGL(to_f16, dim3(1024), dim3(256), 0, stream,
                       x, x_f16, BATCH * D_IN / 4);
    hipLaunchKernelGGL(to_f16, dim3(4096), dim3(256), 0, stream,
                       W_enc, w_f16, D_SAE * D_IN / 4);
    if (f16raw) {
        hipLaunchKernelGGL((gemm_enc_mfma<1>), dim3(BATCH / 128, D_SAE / 128), dim3(256), 0, stream,
                           x_f16, w_f16, b_enc, tau, raw);
        hipLaunchKernelGGL((select_apply<1>), dim3(BATCH), dim3(256), 0, stream,
                           raw, codes, maskp, kptr, x, W_enc, b_enc, tau, cnt, idxl, vall);
    } else {
        hipLaunchKernelGGL((gemm_enc_mfma<0>), dim3(BATCH / 128, D_SAE / 128), dim3(256), 0, stream,
                           x_f16, w_f16, b_enc, tau, raw);
        hipLaunchKernelGGL((select_apply<0>), dim3(BATCH), dim3(256), 0, stream,
                           raw, codes, maskp, kptr, x, W_enc, b_enc, tau, cnt, idxl, vall);
    }
    hipLaunchKernelGGL(transpose_wdec_f16, dim3(D_SAE / 64, D_IN / 64), dim3(256), 0, stream,
                       W_dec, W_decT);
    hipLaunchKernelGGL(recon_sparse, dim3(BATCH), dim3(256), 0, stream,
                       W_decT, cnt, idxl, vall, recon);
}

// Round 7
// 830.997 us; speedup vs baseline: 4.3843x; 1.0264x over previous
//
#include <hip/hip_runtime.h>

#define D_IN   2048
#define D_SAE  16384
#define BATCH  4096
#define CAP    256      // max compacted nonzeros per row
#define MAXB   64       // max boundary-band candidates per row
#define DELTA  1e-2f    // band half-width; >= 2x (gemm f16 err + f16 storage err)

typedef __attribute__((ext_vector_type(8))) _Float16 f16x8;
typedef __attribute__((ext_vector_type(4))) _Float16 f16x4;
typedef __attribute__((ext_vector_type(4))) float f32x4;

// ---------------------------------------------------------------------------
// K0: convert f32 -> f16 (RN).
// ---------------------------------------------------------------------------
__global__ __launch_bounds__(256) void to_f16(const float* __restrict__ in,
                                              ushort* __restrict__ out, int n4) {
    int i = blockIdx.x * blockDim.x + threadIdx.x;
    int stride = gridDim.x * blockDim.x;
    for (; i < n4; i += stride) {
        float4 v = ((const float4*)in)[i];
        ushort4 h;
        float*  vp = (float*)&v;
        ushort* hp = (ushort*)&h;
        #pragma unroll
        for (int j = 0; j < 4; ++j) {
            _Float16 f = (_Float16)vp[j];
            hp[j] = *(ushort*)&f;
        }
        ((ushort4*)out)[i] = h;
    }
}

// ---------------------------------------------------------------------------
// K1: raw[b][s] = relu( x·W_enc[s] + b_enc[s] - tau[s] ), f16 MFMA.
// Round-4 verified structure: 128x128 tile, BK=32, 16 KB LDS, 4 waves,
// global_load_lds width-16, 2-barrier K-loop. CACHED scalar stores (no nt —
// L2 write-combining needs cached partial-line stores; nt caused 1.7x write
// amplification in round 6). XCD-aware bijective block swizzle.
// ---------------------------------------------------------------------------
__device__ __forceinline__ void async_copy16(const void* g, void* l) {
    __builtin_amdgcn_global_load_lds(
        (const __attribute__((address_space(1))) unsigned int*)g,
        (__attribute__((address_space(3))) unsigned int*)l, 16, 0, 0);
}

template<int F16OUT>
__global__ __launch_bounds__(256) void gemm_enc_mfma(
        const ushort* __restrict__ xh,    // x_f16 [4096][2048]
        const ushort* __restrict__ wh,    // w_f16 [16384][2048]
        const float* __restrict__ b_enc,
        const float* __restrict__ tau,
        void* __restrict__ rawout) {
    __shared__ __align__(16) ushort lds[2][128][32];   // A, B = 16 KB
    const int tid  = threadIdx.x;
    const int wid  = tid >> 6;
    const int lane = tid & 63;

    // XCD swizzle: nwg = 32*128 = 4096 = 8*512. XCD k gets a contiguous chunk
    // of 512 tiles = 16 full s-panels -> W panel stays in that XCD's L2.
    const int linear = blockIdx.y * gridDim.x + blockIdx.x;
    const int swz    = (linear & 7) * 512 + (linear >> 3);
    const int m0 = (swz & 31) * 128;   // batch panel
    const int s0 = (swz >> 5) * 128;   // feature panel
    const int wm = wid >> 1, wn = wid & 1;

    const int arr  = wid >> 1;         // 0=A, 1=B
    const int half = wid & 1;          // row half
    const ushort* gsrc = (arr == 0) ? (xh + (size_t)m0 * D_IN)
                                    : (wh + (size_t)s0 * D_IN);
    const ushort* gthread = gsrc + (size_t)(half * 64 + (lane >> 2)) * D_IN + (lane & 3) * 8;

    f32x4 acc[4][4] = {};

    const int fr = lane & 15;
    const int fk = (lane >> 4) * 8;

    for (int k0 = 0; k0 < D_IN; k0 += 32) {
        #pragma unroll
        for (int i = 0; i < 4; ++i)
            async_copy16(gthread + (size_t)i * 16 * D_IN + k0,
                         &lds[arr][half * 64 + i * 16][0]);
        __syncthreads();

        f16x8 a[4], b[4];
        #pragma unroll
        for (int f = 0; f < 4; ++f) {
            a[f] = *(const f16x8*)&lds[0][wm * 64 + f * 16 + fr][fk];
            b[f] = *(const f16x8*)&lds[1][wn * 64 + f * 16 + fr][fk];
        }
        #pragma unroll
        for (int i = 0; i < 4; ++i)
            #pragma unroll
            for (int j = 0; j < 4; ++j)
                acc[i][j] = __builtin_amdgcn_mfma_f32_16x16x32_f16(a[i], b[j], acc[i][j], 0, 0, 0);
        __syncthreads();
    }

    // epilogue: + b_enc - tau, relu; C/D layout col=lane&15, row=(lane>>4)*4+reg
    const int fq = lane >> 4;
    #pragma unroll
    for (int j = 0; j < 4; ++j) {
        int col = s0 + wn * 64 + j * 16 + fr;
        float be = b_enc[col] - tau[col];
        #pragma unroll
        for (int i = 0; i < 4; ++i) {
            int rbase = m0 + wm * 64 + i * 16 + fq * 4;
            #pragma unroll
            for (int r = 0; r < 4; ++r) {
                float v = fmaxf(acc[i][j][r] + be, 0.f);
                size_t ofs = (size_t)(rbase + r) * D_SAE + col;
                if (F16OUT) {
                    _Float16 hv = (_Float16)v;
                    ((ushort*)rawout)[ofs] = *(ushort*)&hv;
                } else {
                    ((float*)rawout)[ofs] = v;
                }
            }
        }
    }
}

// ---------------------------------------------------------------------------
// K2: transpose W_dec (f32 [2048][16384]) -> W_decT (f16 [16384][2048])
// ---------------------------------------------------------------------------
__global__ __launch_bounds__(256) void transpose_wdec_f16(const float* __restrict__ W_dec,
                                                          _Float16* __restrict__ W_decT) {
    __shared__ float t[64][65];
    const int tid = threadIdx.x;
    const int x0 = blockIdx.x * 64;   // feature (s)
    const int y0 = blockIdx.y * 64;   // d_in (i)
    const int tx = tid & 15;
    const int ty = tid >> 4;
    #pragma unroll
    for (int p = 0; p < 4; ++p) {
        float4 v = *(const float4*)&W_dec[(size_t)(y0 + p * 16 + ty) * D_SAE + x0 + tx * 4];
        t[p * 16 + ty][tx * 4 + 0] = v.x;
        t[p * 16 + ty][tx * 4 + 1] = v.y;
        t[p * 16 + ty][tx * 4 + 2] = v.z;
        t[p * 16 + ty][tx * 4 + 3] = v.w;
    }
    __syncthreads();
    #pragma unroll
    for (int p = 0; p < 4; ++p) {
        int s = p * 16 + ty;
        f16x4 o;
        #pragma unroll
        for (int q = 0; q < 4; ++q)
            o[q] = (_Float16)t[tx * 4 + q][s];
        *(f16x4*)&W_decT[(size_t)(x0 + s) * D_IN + y0 + tx * 4] = o;
    }
}

// ---------------------------------------------------------------------------
// K3: exact rank-K select. Histogram kth localization (2 passes over f16 bit
// patterns, monotone for non-negative values), then f64 band refinement
// (exact when DELTA >= 2 * max approx error). s = i*2048 + tid*8 + j.
// ---------------------------------------------------------------------------
template<int SRC16>
__global__ __launch_bounds__(256) void select_apply(
        const void* __restrict__ rawsrc,
        float* __restrict__ codes, float* __restrict__ mask,
        const int* __restrict__ kptr,
        const float* __restrict__ x, const float* __restrict__ W_enc,
        const float* __restrict__ b_enc, const float* __restrict__ tau,
        int* __restrict__ cnt_out, int* __restrict__ idx_out,
        float* __restrict__ val_out) {
    const int row = blockIdx.x;
    const int tid = threadIdx.x;
    const long base = (long)row * D_SAE;

    float c[8][8];
    if (SRC16) {
        const ushort* rh = (const ushort*)rawsrc;
        #pragma unroll
        for (int i = 0; i < 8; ++i) {
            uint4 u = *(const uint4*)(rh + base + i * 2048 + tid * 8);
            const unsigned* up = (const unsigned*)&u;
            #pragma unroll
            for (int q = 0; q < 4; ++q) {
                ushort b0 = (ushort)(up[q] & 0xFFFFu), b1 = (ushort)(up[q] >> 16);
                _Float16 h0, h1;
                *(ushort*)&h0 = b0; *(ushort*)&h1 = b1;
                c[i][2 * q]     = (float)h0;
                c[i][2 * q + 1] = (float)h1;
            }
        }
    } else {
        const float* rf = (const float*)rawsrc;
        #pragma unroll
        for (int i = 0; i < 8; ++i) {
            float4 v0 = *(const float4*)(rf + base + i * 2048 + tid * 8);
            float4 v1 = *(const float4*)(rf + base + i * 2048 + tid * 8 + 4);
            c[i][0] = v0.x; c[i][1] = v0.y; c[i][2] = v0.z; c[i][3] = v0.w;
            c[i][4] = v1.x; c[i][5] = v1.y; c[i][6] = v1.z; c[i][7] = v1.w;
        }
    }

    int K = kptr[0];
    if (K > D_SAE) K = D_SAE;

    __shared__ int    hist[1024];
    __shared__ int    scan[256];
    __shared__ int    wsum[4];
    __shared__ int    bidx[MAXB];
    __shared__ double exactv[MAXB];
    __shared__ int    selfl[MAXB];
    __shared__ double dsum[4];
    __shared__ int    sh_B, sh_nAB, sh_kpat;

    // --- 1a) histogram of f16-pattern top-10 bits (1024 buckets)
    #pragma unroll
    for (int q = 0; q < 4; ++q) hist[tid + q * 256] = 0;
    if (tid == 0) { sh_B = -1; sh_nAB = 0; }
    __syncthreads();
    #pragma unroll
    for (int i = 0; i < 8; ++i)
        #pragma unroll
        for (int j = 0; j < 8; ++j) {
            _Float16 h = (_Float16)c[i][j];
            ushort pat = *(ushort*)&h;
            if (pat) atomicAdd(&hist[pat >> 6], 1);
        }
    __syncthreads();

    // --- 1b) suffix scan over buckets (thread tid owns buckets 4t..4t+3)
    int s_loc = hist[4 * tid] + hist[4 * tid + 1] + hist[4 * tid + 2] + hist[4 * tid + 3];
    const int my = 255 - tid;
    scan[my] = s_loc;
    __syncthreads();
    #pragma unroll
    for (int off = 1; off < 256; off <<= 1) {
        int a = scan[my];
        int b = (my >= off) ? scan[my - off] : 0;
        __syncthreads();
        scan[my] = a + b;
        __syncthreads();
    }
    int I = scan[my];        // count of elements in buckets >= 4*tid
    int E = I - s_loc;       // count in buckets >= 4*(tid+1)
    if (I >= K && E < K) {   // exactly one thread (when enough positives)
        int cnt = E, b;
        for (b = 4 * tid + 3; b > 4 * tid; --b) {
            cnt += hist[b];
            if (cnt >= K) break;
        }
        if (cnt < K) { cnt += hist[4 * tid]; b = 4 * tid; }
        sh_B = b;
        sh_nAB = cnt - hist[b];    // elements strictly above bucket B
    }
    __syncthreads();
    const int B = sh_B, nAB = sh_nAB;

    // --- 1c) second pass within bucket B (low 6 bits)
    if (tid < 64) hist[tid] = 0;
    __syncthreads();
    if (B >= 0) {
        #pragma unroll
        for (int i = 0; i < 8; ++i)
            #pragma unroll
            for (int j = 0; j < 8; ++j) {
                _Float16 h = (_Float16)c[i][j];
                ushort pat = *(ushort*)&h;
                if (pat && (int)(pat >> 6) == B) atomicAdd(&hist[pat & 63], 1);
            }
    }
    __syncthreads();
    if (tid == 0) {
        int kpat = 0;
        if (B >= 0) {
            int cnt = nAB, l;
            for (l = 63; l >= 0; --l) {
                cnt += hist[l];
                if (cnt >= K) break;
            }
            if (l < 0) l = 0;
            kpat = (B << 6) | l;
        }
        sh_kpat = kpat;
    }
    __syncthreads();
    _Float16 kh; *(ushort*)&kh = (ushort)sh_kpat;
    const float kf = (float)kh;
    const float thr_hi = kf + DELTA;
    const float thr_lo = kf - DELTA;

    // --- 2) count above / collect band
    int cA = 0, cB2 = 0;
    #pragma unroll
    for (int i = 0; i < 8; ++i)
        #pragma unroll
        for (int j = 0; j < 8; ++j) {
            float cc = c[i][j];
            cA  += (cc > thr_hi);
            cB2 += (cc >= thr_lo) && (cc <= thr_hi);
        }
    {
        int a = cA;
        #pragma unroll
        for (int off = 32; off; off >>= 1) a += __shfl_xor(a, off, 64);
        if ((tid & 63) == 0) wsum[tid >> 6] = a;
    }
    __syncthreads();
    const int nA = wsum[0] + wsum[1] + wsum[2] + wsum[3];
    __syncthreads();

    scan[tid] = cB2;
    __syncthreads();
    #pragma unroll
    for (int off = 1; off < 256; off <<= 1) {
        int a = scan[tid];
        int b = (tid >= off) ? scan[tid - off] : 0;
        __syncthreads();
        scan[tid] = a + b;
        __syncthreads();
    }
    int posB = scan[tid] - cB2;
    int nb   = scan[255];
    if (nb > MAXB) nb = MAXB;

    {
        int p = posB;
        #pragma unroll
        for (int i = 0; i < 8; ++i)
            #pragma unroll
            for (int j = 0; j < 8; ++j) {
                float cc = c[i][j];
                if ((cc >= thr_lo) && (cc <= thr_hi)) {
                    if (p < MAXB) bidx[p] = i * 2048 + tid * 8 + j;
                    ++p;
                }
            }
    }
    __syncthreads();

    // --- 3) exact f64 pre for band candidates
    const float* xrow = x + (size_t)row * D_IN;
    for (int jj = 0; jj < nb; ++jj) {
        int s = bidx[jj];
        const float* wrow = W_enc + (size_t)s * D_IN;
        double a = 0.0;
        #pragma unroll
        for (int q = 0; q < 8; ++q)
            a += (double)xrow[tid * 8 + q] * (double)wrow[tid * 8 + q];
        #pragma unroll
        for (int off = 32; off; off >>= 1) a += __shfl_xor(a, off, 64);
        if ((tid & 63) == 0) dsum[tid >> 6] = a;
        __syncthreads();
        if (tid == 0)
            exactv[jj] = dsum[0] + dsum[1] + dsum[2] + dsum[3]
                         + (double)b_enc[s] - (double)tau[s];
        __syncthreads();
    }

    int m = K - nA;
    if (m > nb) m = nb;
    if (tid < nb) {
        double e = exactv[tid];
        int rank = 0;
        for (int l = 0; l < nb; ++l) rank += (exactv[l] > e);
        selfl[tid] = (rank < m) ? 1 : 0;
    }
    __syncthreads();

    // per-thread override bits: owner tid = (s>>3)&255, bit = (s>>11)*8 + (s&7)
    unsigned long long ov = 0ull;
    for (int jj = 0; jj < nb; ++jj) {
        int s = bidx[jj];
        if (((s >> 3) & 255) == tid && selfl[jj])
            ov |= 1ull << (((s >> 11) << 3) | (s & 7));
    }

    // --- 4) final keep predicate, compaction, writes
    int kc = 0;
    #pragma unroll
    for (int i = 0; i < 8; ++i)
        #pragma unroll
        for (int j = 0; j < 8; ++j) {
            float cc = c[i][j];
            bool sel = (cc > thr_hi) || ((ov >> (i * 8 + j)) & 1ull);
            kc += sel && (cc > 0.f);
        }
    __syncthreads();
    scan[tid] = kc;
    __syncthreads();
    #pragma unroll
    for (int off = 1; off < 256; off <<= 1) {
        int a = scan[tid];
        int b = (tid >= off) ? scan[tid - off] : 0;
        __syncthreads();
        scan[tid] = a + b;
        __syncthreads();
    }
    int pos   = scan[tid] - kc;
    int total = scan[255];

    #pragma unroll
    for (int i = 0; i < 8; ++i) {
        f32x4 cf0, cf1, mf0, mf1;
        #pragma unroll
        for (int j = 0; j < 8; ++j) {
            float cc = c[i][j];
            bool sel = (cc > thr_hi) || ((ov >> (i * 8 + j)) & 1ull);
            bool m_  = sel && (cc > 0.f);
            float cv = sel ? cc : 0.f;
            float mv = m_ ? 1.f : 0.f;
            if (j < 4) { cf0[j] = cv; mf0[j] = mv; }
            else       { cf1[j - 4] = cv; mf1[j - 4] = mv; }
            if (m_) {
                if (pos < CAP) {
                    idx_out[row * CAP + pos] = i * 2048 + tid * 8 + j;
                    val_out[row * CAP + pos] = cv;
                }
                ++pos;
            }
        }
        long o = base + i * 2048 + tid * 8;
        __builtin_nontemporal_store(cf0, (f32x4*)(codes + o));
        __builtin_nontemporal_store(cf1, (f32x4*)(codes + o + 4));
        __builtin_nontemporal_store(mf0, (f32x4*)(mask + o));
        __builtin_nontemporal_store(mf1, (f32x4*)(mask + o + 4));
    }
    if (tid == 0) cnt_out[row] = total < CAP ? total : CAP;
}

// ---------------------------------------------------------------------------
// K4: recon[b,:] = sum_j val_j * W_decT16[idx_j, :]   (f16 gather, f32 accum)
// ---------------------------------------------------------------------------
__global__ __launch_bounds__(256) void recon_sparse(const _Float16* __restrict__ Wd16,
                                                    const int* __restrict__ cnt,
                                                    const int* __restrict__ idx,
                                                    const float* __restrict__ val,
                                                    float* __restrict__ recon) {
    const int row = blockIdx.x;
    const int tid = threadIdx.x;
    __shared__ int   s_idx[CAP];
    __shared__ float s_val[CAP];
    const int n = cnt[row];
    for (int j = tid; j < n; j += 256) {
        s_idx[j] = idx[row * CAP + j];
        s_val[j] = val[row * CAP + j];
    }
    __syncthreads();

    float4 a0 = {0.f, 0.f, 0.f, 0.f};
    float4 a1 = {0.f, 0.f, 0.f, 0.f};
    for (int j = 0; j < n; ++j) {
        float c = s_val[j];
        const _Float16* w = Wd16 + (size_t)s_idx[j] * D_IN;
        f16x4 w0 = *(const f16x4*)(w + tid * 4);
        f16x4 w1 = *(const f16x4*)(w + 1024 + tid * 4);
        a0.x = fmaf(c, (float)w0[0], a0.x); a0.y = fmaf(c, (float)w0[1], a0.y);
        a0.z = fmaf(c, (float)w0[2], a0.z); a0.w = fmaf(c, (float)w0[3], a0.w);
        a1.x = fmaf(c, (float)w1[0], a1.x); a1.y = fmaf(c, (float)w1[1], a1.y);
        a1.z = fmaf(c, (float)w1[2], a1.z); a1.w = fmaf(c, (float)w1[3], a1.w);
    }
    float* out = recon + (size_t)row * D_IN;
    *(float4*)(out + tid * 4)        = a0;
    *(float4*)(out + 1024 + tid * 4) = a1;
}

// ---------------------------------------------------------------------------
// Workspace:
//  f16-raw path (needs ~216.3 MB):
//   [0,64M)    w_f16 (phase A) / W_decT f16 (phase B, after select)
//   [64M,80M)  x_f16
//   [80M,208M) raw f16 codes
//   [208M,..)  cnt (16K), idx (4M), val (4M)
//  fallback (ws too small, ~88.3 MB): raw f32 lives in d_out codes region,
//   cnt/idx/val at 80M.
// ---------------------------------------------------------------------------
extern "C" void kernel_launch(void* const* d_in, const int* in_sizes, int n_in,
                              void* d_out, int out_size, void* d_ws, size_t ws_size,
                              hipStream_t stream) {
    const float* x     = (const float*)d_in[0];
    const float* W_enc = (const float*)d_in[1];
    const float* b_enc = (const float*)d_in[2];
    const float* tau   = (const float*)d_in[3];
    const float* W_dec = (const float*)d_in[4];
    const int*   kptr  = (const int*)d_in[5];

    float* recon = (float*)d_out;
    float* codes = recon + (size_t)BATCH * D_IN;
    float* maskp = codes + (size_t)BATCH * D_SAE;

    char* w = (char*)d_ws;
    const size_t OFF_X   = (size_t)D_SAE * D_IN * 2;             // 64M
    const size_t OFF_RAW = OFF_X + (size_t)BATCH * D_IN * 2;     // 80M
    const size_t RAWSZ   = (size_t)BATCH * D_SAE * 2;            // 128M
    const size_t TAILSZ  = 16384 + 2 * (size_t)BATCH * CAP * 4;  // cnt+idx+val
    const bool f16raw = ws_size >= OFF_RAW + RAWSZ + TAILSZ;

    const size_t OFF_CNT = f16raw ? (OFF_RAW + RAWSZ) : OFF_RAW;
    ushort*   w_f16  = (ushort*)w;
    ushort*   x_f16  = (ushort*)(w + OFF_X);
    _Float16* W_decT = (_Float16*)w;                             // phase B
    int*      cnt    = (int*)  (w + OFF_CNT);
    int*      idxl   = (int*)  (w + OFF_CNT + 16384);
    float*    vall   = (float*)(w + OFF_CNT + 16384 + (size_t)BATCH * CAP * 4);
    void*     raw    = f16raw ? (void*)(w + OFF_RAW) : (void*)codes;

    hipLaunchKernelGGL(to_f16, dim3(1024), dim3(256), 0, stream,
                       x, x_f16, BATCH * D_IN / 4);
    hipLaunchKernelGGL(to_f16, dim3(4096), dim3(256), 0, stream,
                       W_enc, w_f16, D_SAE * D_IN / 4);
    if (f16raw) {
        hipLaunchKernelGGL((gemm_enc_mfma<1>), dim3(BATCH / 128, D_SAE / 128), dim3(256), 0, stream,
                           x_f16, w_f16, b_enc, tau, raw);
        hipLaunchKernelGGL((select_apply<1>), dim3(BATCH), dim3(256), 0, stream,
                           raw, codes, maskp, kptr, x, W_enc, b_enc, tau, cnt, idxl, vall);
    } else {
        hipLaunchKernelGGL((gemm_enc_mfma<0>), dim3(BATCH / 128, D_SAE / 128), dim3(256), 0, stream,
                           x_f16, w_f16, b_enc, tau, raw);
        hipLaunchKernelGGL((select_apply<0>), dim3(BATCH), dim3(256), 0, stream,
                           raw, codes, maskp, kptr, x, W_enc, b_enc, tau, cnt, idxl, vall);
    }
    hipLaunchKernelGGL(transpose_wdec_f16, dim3(D_SAE / 64, D_IN / 64), dim3(256), 0, stream,
                       W_dec, W_decT);
    hipLaunchKernelGGL(recon_sparse, dim3(BATCH), dim3(256), 0, stream,
                       W_decT, cnt, idxl, vall, recon);
}

// Round 8
// 701.804 us; speedup vs baseline: 5.1914x; 1.1841x over previous
//
#include <hip/hip_runtime.h>

#define D_IN   2048
#define D_SAE  16384
#define BATCH  4096
#define CAP    256      // max compacted nonzeros per row
#define MAXB   64       // max boundary-band candidates per row
#define DELTA  1e-2f    // band half-width; >= 2x (gemm f16 err + f16 storage err)

typedef __attribute__((ext_vector_type(8))) _Float16 f16x8;
typedef __attribute__((ext_vector_type(4))) _Float16 f16x4;
typedef __attribute__((ext_vector_type(4))) float f32x4;

// ---------------------------------------------------------------------------
// K0: convert f32 -> f16 (RN).
// ---------------------------------------------------------------------------
__global__ __launch_bounds__(256) void to_f16(const float* __restrict__ in,
                                              ushort* __restrict__ out, int n4) {
    int i = blockIdx.x * blockDim.x + threadIdx.x;
    int stride = gridDim.x * blockDim.x;
    for (; i < n4; i += stride) {
        float4 v = ((const float4*)in)[i];
        ushort4 h;
        float*  vp = (float*)&v;
        ushort* hp = (ushort*)&h;
        #pragma unroll
        for (int j = 0; j < 4; ++j) {
            _Float16 f = (_Float16)vp[j];
            hp[j] = *(ushort*)&f;
        }
        ((ushort4*)out)[i] = h;
    }
}

// ---------------------------------------------------------------------------
// K1: raw[b][s] = relu( x·W_enc[s] + b_enc[s] - tau[s] ), f16 MFMA.
// 256x256 tile, BK=64, 8 waves (2M x 4N), 128 KB double-buffered LDS,
// 4 phases per K-tile: {stage 1 half-tile || 12 swizzled ds_read_b128 ->
// s_barrier -> setprio(1) -> 16 MFMA -> setprio(0) -> s_barrier}. Counted
// vmcnt(0) once per K-tile boundary (covers exactly the 8 in-flight loads,
// issued 1-4 phases earlier). LDS bank-conflict-free via chunk rotation:
// slot p stores logical 16B-chunk c with p=(c+row)&7; global_load_lds dest
// stays LINEAR, per-lane GLOBAL source is inverse-rotated, ds_read applies
// the rotation (both-sides-or-neither rule).
// ---------------------------------------------------------------------------
__device__ __forceinline__ void async_copy16(const void* g, void* l) {
    __builtin_amdgcn_global_load_lds(
        (const __attribute__((address_space(1))) unsigned int*)g,
        (__attribute__((address_space(3))) unsigned int*)l, 16, 0, 0);
}

template<int F16OUT>
__global__ __launch_bounds__(512) void gemm_enc_mfma(
        const ushort* __restrict__ xh,    // x_f16 [4096][2048]
        const ushort* __restrict__ wh,    // w_f16 [16384][2048]
        const float* __restrict__ b_enc,
        const float* __restrict__ tau,
        void* __restrict__ rawout) {
    // [buf][A=0/B=1][half][128 rows][8 slots][8 f16] = 128 KB
    __shared__ ushort lds[2][2][2][8192];

    const int tid  = threadIdx.x;
    const int w    = tid >> 6;         // wave 0..7
    const int lane = tid & 63;
    const int wm   = w >> 2;           // 0..1 (M)
    const int wn   = w & 3;            // 0..3 (N)
    const int m0 = blockIdx.x * 256;
    const int s0 = blockIdx.y * 256;

    const int fr = lane & 15;
    const int fq = lane >> 4;          // 0..3

    // staging geometry: issue q stages rows q*64+w*8+(lane>>3), slot lane&7
    const int srow0 = w * 8 + (lane >> 3);     // q=0 row in half (0..63)
    const int srow1 = 64 + srow0;              // q=1 row
    const int sc0i  = ((lane & 7) - srow0 & 7) * 8;  // inverse-rotated chunk, ushort units

    const ushort* panelA = xh + (size_t)m0 * 2048;
    const ushort* panelB = wh + (size_t)s0 * 2048;

    auto stage_half = [&](int bufi, int ab, int h, int koff) {
        const ushort* gp = (ab == 0) ? panelA : panelB;
        const ushort* g0 = gp + (size_t)(h * 128 + srow0) * 2048 + koff + sc0i;
        const ushort* g1 = gp + (size_t)(h * 128 + srow1) * 2048 + koff + sc0i;
        async_copy16(g0, &lds[bufi][ab][h][w * 512]);
        async_copy16(g1, &lds[bufi][ab][h][4096 + w * 512]);
    };

    // fragment read offsets (ushort units), t-invariant:
    // row r, chunk c=kk*4+fq -> addr = r*64 + ((c+r)&7)*8
    int a_off[8][2], b_off[4][2];
    #pragma unroll
    for (int m = 0; m < 8; ++m) {
        int r = m * 16 + fr;
        #pragma unroll
        for (int kk = 0; kk < 2; ++kk)
            a_off[m][kk] = r * 64 + (((kk * 4 + fq) + r) & 7) * 8;
    }
    #pragma unroll
    for (int g = 0; g < 4; ++g) {
        int r = (wn & 1) * 64 + g * 16 + fr;
        #pragma unroll
        for (int kk = 0; kk < 2; ++kk)
            b_off[g][kk] = r * 64 + (((kk * 4 + fq) + r) & 7) * 8;
    }

    f32x4 acc[8][4] = {};

    // prologue: stage K-tile 0 fully into buf 0
    stage_half(0, 0, 0, 0);
    stage_half(0, 0, 1, 0);
    stage_half(0, 1, 0, 0);
    stage_half(0, 1, 1, 0);
    asm volatile("s_waitcnt vmcnt(0)" ::: "memory");
    asm volatile("s_barrier" ::: "memory");

#define PHASE(QM, QN, AB, H)                                                   \
    do {                                                                       \
        if (t < 31) stage_half(nbuf, AB, H, knext);                            \
        f16x8 af[4][2], bf[2][2];                                              \
        _Pragma("unroll") for (int mm = 0; mm < 4; ++mm)                       \
            _Pragma("unroll") for (int kk = 0; kk < 2; ++kk)                   \
                af[mm][kk] = *(const f16x8*)&ldsA[a_off[(QM) * 4 + mm][kk]];   \
        _Pragma("unroll") for (int nn = 0; nn < 2; ++nn)                       \
            _Pragma("unroll") for (int kk = 0; kk < 2; ++kk)                   \
                bf[nn][kk] = *(const f16x8*)&ldsB[b_off[(QN) * 2 + nn][kk]];   \
        asm volatile("s_barrier" ::: "memory");                                \
        __builtin_amdgcn_s_setprio(1);                                         \
        _Pragma("unroll") for (int kk = 0; kk < 2; ++kk)                       \
            _Pragma("unroll") for (int mm = 0; mm < 4; ++mm)                   \
                _Pragma("unroll") for (int nn = 0; nn < 2; ++nn)               \
                    acc[(QM) * 4 + mm][(QN) * 2 + nn] =                        \
                        __builtin_amdgcn_mfma_f32_16x16x32_f16(                \
                            af[mm][kk], bf[nn][kk],                            \
                            acc[(QM) * 4 + mm][(QN) * 2 + nn], 0, 0, 0);       \
        __builtin_amdgcn_s_setprio(0);                                         \
        asm volatile("s_barrier" ::: "memory");                                \
    } while (0)

    for (int t = 0; t < 32; ++t) {
        const int cbuf = t & 1, nbuf = cbuf ^ 1;
        const int knext = (t + 1) * 64;
        const ushort* ldsA = &lds[cbuf][0][wm][0];
        const ushort* ldsB = &lds[cbuf][1][wn >> 1][0];
        PHASE(0, 0, 0, 0);
        PHASE(0, 1, 0, 1);
        PHASE(1, 0, 1, 0);
        PHASE(1, 1, 1, 1);
        asm volatile("s_waitcnt vmcnt(0)" ::: "memory");
        asm volatile("s_barrier" ::: "memory");
    }
#undef PHASE

    // epilogue: + b_enc - tau, relu; C/D layout col=fr, row=fq*4+r
    float bias[4];
    int col[4];
    #pragma unroll
    for (int n = 0; n < 4; ++n) {
        col[n] = s0 + wn * 64 + n * 16 + fr;
        bias[n] = b_enc[col[n]] - tau[col[n]];
    }
    #pragma unroll
    for (int m = 0; m < 8; ++m) {
        int rbase = m0 + wm * 128 + m * 16 + fq * 4;
        #pragma unroll
        for (int n = 0; n < 4; ++n) {
            #pragma unroll
            for (int r = 0; r < 4; ++r) {
                float v = fmaxf(acc[m][n][r] + bias[n], 0.f);
                size_t ofs = (size_t)(rbase + r) * D_SAE + col[n];
                if (F16OUT) {
                    _Float16 hv = (_Float16)v;
                    ((ushort*)rawout)[ofs] = *(ushort*)&hv;
                } else {
                    ((float*)rawout)[ofs] = v;
                }
            }
        }
    }
}

// ---------------------------------------------------------------------------
// K2: transpose W_dec (f32 [2048][16384]) -> W_decT (f16 [16384][2048])
// ---------------------------------------------------------------------------
__global__ __launch_bounds__(256) void transpose_wdec_f16(const float* __restrict__ W_dec,
                                                          _Float16* __restrict__ W_decT) {
    __shared__ float t[64][65];
    const int tid = threadIdx.x;
    const int x0 = blockIdx.x * 64;   // feature (s)
    const int y0 = blockIdx.y * 64;   // d_in (i)
    const int tx = tid & 15;
    const int ty = tid >> 4;
    #pragma unroll
    for (int p = 0; p < 4; ++p) {
        float4 v = *(const float4*)&W_dec[(size_t)(y0 + p * 16 + ty) * D_SAE + x0 + tx * 4];
        t[p * 16 + ty][tx * 4 + 0] = v.x;
        t[p * 16 + ty][tx * 4 + 1] = v.y;
        t[p * 16 + ty][tx * 4 + 2] = v.z;
        t[p * 16 + ty][tx * 4 + 3] = v.w;
    }
    __syncthreads();
    #pragma unroll
    for (int p = 0; p < 4; ++p) {
        int s = p * 16 + ty;
        f16x4 o;
        #pragma unroll
        for (int q = 0; q < 4; ++q)
            o[q] = (_Float16)t[tx * 4 + q][s];
        *(f16x4*)&W_decT[(size_t)(x0 + s) * D_IN + y0 + tx * 4] = o;
    }
}

// ---------------------------------------------------------------------------
// K3: exact rank-K select. Histogram kth localization (2 passes over f16 bit
// patterns, monotone for non-negative values), then f64 band refinement
// (exact when DELTA >= 2 * max approx error). s = i*2048 + tid*8 + j.
// ---------------------------------------------------------------------------
template<int SRC16>
__global__ __launch_bounds__(256) void select_apply(
        const void* __restrict__ rawsrc,
        float* __restrict__ codes, float* __restrict__ mask,
        const int* __restrict__ kptr,
        const float* __restrict__ x, const float* __restrict__ W_enc,
        const float* __restrict__ b_enc, const float* __restrict__ tau,
        int* __restrict__ cnt_out, int* __restrict__ idx_out,
        float* __restrict__ val_out) {
    const int row = blockIdx.x;
    const int tid = threadIdx.x;
    const long base = (long)row * D_SAE;

    float c[8][8];
    if (SRC16) {
        const ushort* rh = (const ushort*)rawsrc;
        #pragma unroll
        for (int i = 0; i < 8; ++i) {
            uint4 u = *(const uint4*)(rh + base + i * 2048 + tid * 8);
            const unsigned* up = (const unsigned*)&u;
            #pragma unroll
            for (int q = 0; q < 4; ++q) {
                ushort b0 = (ushort)(up[q] & 0xFFFFu), b1 = (ushort)(up[q] >> 16);
                _Float16 h0, h1;
                *(ushort*)&h0 = b0; *(ushort*)&h1 = b1;
                c[i][2 * q]     = (float)h0;
                c[i][2 * q + 1] = (float)h1;
            }
        }
    } else {
        const float* rf = (const float*)rawsrc;
        #pragma unroll
        for (int i = 0; i < 8; ++i) {
            float4 v0 = *(const float4*)(rf + base + i * 2048 + tid * 8);
            float4 v1 = *(const float4*)(rf + base + i * 2048 + tid * 8 + 4);
            c[i][0] = v0.x; c[i][1] = v0.y; c[i][2] = v0.z; c[i][3] = v0.w;
            c[i][4] = v1.x; c[i][5] = v1.y; c[i][6] = v1.z; c[i][7] = v1.w;
        }
    }

    int K = kptr[0];
    if (K > D_SAE) K = D_SAE;

    __shared__ int    hist[1024];
    __shared__ int    scan[256];
    __shared__ int    wsum[4];
    __shared__ int    bidx[MAXB];
    __shared__ double exactv[MAXB];
    __shared__ int    selfl[MAXB];
    __shared__ double dsum[4];
    __shared__ int    sh_B, sh_nAB, sh_kpat;

    // --- 1a) histogram of f16-pattern top-10 bits (1024 buckets)
    #pragma unroll
    for (int q = 0; q < 4; ++q) hist[tid + q * 256] = 0;
    if (tid == 0) { sh_B = -1; sh_nAB = 0; }
    __syncthreads();
    #pragma unroll
    for (int i = 0; i < 8; ++i)
        #pragma unroll
        for (int j = 0; j < 8; ++j) {
            _Float16 h = (_Float16)c[i][j];
            ushort pat = *(ushort*)&h;
            if (pat) atomicAdd(&hist[pat >> 6], 1);
        }
    __syncthreads();

    // --- 1b) suffix scan over buckets (thread tid owns buckets 4t..4t+3)
    int s_loc = hist[4 * tid] + hist[4 * tid + 1] + hist[4 * tid + 2] + hist[4 * tid + 3];
    const int my = 255 - tid;
    scan[my] = s_loc;
    __syncthreads();
    #pragma unroll
    for (int off = 1; off < 256; off <<= 1) {
        int a = scan[my];
        int b = (my >= off) ? scan[my - off] : 0;
        __syncthreads();
        scan[my] = a + b;
        __syncthreads();
    }
    int I = scan[my];        // count of elements in buckets >= 4*tid
    int E = I - s_loc;       // count in buckets >= 4*(tid+1)
    if (I >= K && E < K) {   // exactly one thread (when enough positives)
        int cnt = E, b;
        for (b = 4 * tid + 3; b > 4 * tid; --b) {
            cnt += hist[b];
            if (cnt >= K) break;
        }
        if (cnt < K) { cnt += hist[4 * tid]; b = 4 * tid; }
        sh_B = b;
        sh_nAB = cnt - hist[b];    // elements strictly above bucket B
    }
    __syncthreads();
    const int B = sh_B, nAB = sh_nAB;

    // --- 1c) second pass within bucket B (low 6 bits)
    if (tid < 64) hist[tid] = 0;
    __syncthreads();
    if (B >= 0) {
        #pragma unroll
        for (int i = 0; i < 8; ++i)
            #pragma unroll
            for (int j = 0; j < 8; ++j) {
                _Float16 h = (_Float16)c[i][j];
                ushort pat = *(ushort*)&h;
                if (pat && (int)(pat >> 6) == B) atomicAdd(&hist[pat & 63], 1);
            }
    }
    __syncthreads();
    if (tid == 0) {
        int kpat = 0;
        if (B >= 0) {
            int cnt = nAB, l;
            for (l = 63; l >= 0; --l) {
                cnt += hist[l];
                if (cnt >= K) break;
            }
            if (l < 0) l = 0;
            kpat = (B << 6) | l;
        }
        sh_kpat = kpat;
    }
    __syncthreads();
    _Float16 kh; *(ushort*)&kh = (ushort)sh_kpat;
    const float kf = (float)kh;
    const float thr_hi = kf + DELTA;
    const float thr_lo = kf - DELTA;

    // --- 2) count above / collect band
    int cA = 0, cB2 = 0;
    #pragma unroll
    for (int i = 0; i < 8; ++i)
        #pragma unroll
        for (int j = 0; j < 8; ++j) {
            float cc = c[i][j];
            cA  += (cc > thr_hi);
            cB2 += (cc >= thr_lo) && (cc <= thr_hi);
        }
    {
        int a = cA;
        #pragma unroll
        for (int off = 32; off; off >>= 1) a += __shfl_xor(a, off, 64);
        if ((tid & 63) == 0) wsum[tid >> 6] = a;
    }
    __syncthreads();
    const int nA = wsum[0] + wsum[1] + wsum[2] + wsum[3];
    __syncthreads();

    scan[tid] = cB2;
    __syncthreads();
    #pragma unroll
    for (int off = 1; off < 256; off <<= 1) {
        int a = scan[tid];
        int b = (tid >= off) ? scan[tid - off] : 0;
        __syncthreads();
        scan[tid] = a + b;
        __syncthreads();
    }
    int posB = scan[tid] - cB2;
    int nb   = scan[255];
    if (nb > MAXB) nb = MAXB;

    {
        int p = posB;
        #pragma unroll
        for (int i = 0; i < 8; ++i)
            #pragma unroll
            for (int j = 0; j < 8; ++j) {
                float cc = c[i][j];
                if ((cc >= thr_lo) && (cc <= thr_hi)) {
                    if (p < MAXB) bidx[p] = i * 2048 + tid * 8 + j;
                    ++p;
                }
            }
    }
    __syncthreads();

    // --- 3) exact f64 pre for band candidates
    const float* xrow = x + (size_t)row * D_IN;
    for (int jj = 0; jj < nb; ++jj) {
        int s = bidx[jj];
        const float* wrow = W_enc + (size_t)s * D_IN;
        double a = 0.0;
        #pragma unroll
        for (int q = 0; q < 8; ++q)
            a += (double)xrow[tid * 8 + q] * (double)wrow[tid * 8 + q];
        #pragma unroll
        for (int off = 32; off; off >>= 1) a += __shfl_xor(a, off, 64);
        if ((tid & 63) == 0) dsum[tid >> 6] = a;
        __syncthreads();
        if (tid == 0)
            exactv[jj] = dsum[0] + dsum[1] + dsum[2] + dsum[3]
                         + (double)b_enc[s] - (double)tau[s];
        __syncthreads();
    }

    int m = K - nA;
    if (m > nb) m = nb;
    if (tid < nb) {
        double e = exactv[tid];
        int rank = 0;
        for (int l = 0; l < nb; ++l) rank += (exactv[l] > e);
        selfl[tid] = (rank < m) ? 1 : 0;
    }
    __syncthreads();

    // per-thread override bits: owner tid = (s>>3)&255, bit = (s>>11)*8 + (s&7)
    unsigned long long ov = 0ull;
    for (int jj = 0; jj < nb; ++jj) {
        int s = bidx[jj];
        if (((s >> 3) & 255) == tid && selfl[jj])
            ov |= 1ull << (((s >> 11) << 3) | (s & 7));
    }

    // --- 4) final keep predicate, compaction, writes
    int kc = 0;
    #pragma unroll
    for (int i = 0; i < 8; ++i)
        #pragma unroll
        for (int j = 0; j < 8; ++j) {
            float cc = c[i][j];
            bool sel = (cc > thr_hi) || ((ov >> (i * 8 + j)) & 1ull);
            kc += sel && (cc > 0.f);
        }
    __syncthreads();
    scan[tid] = kc;
    __syncthreads();
    #pragma unroll
    for (int off = 1; off < 256; off <<= 1) {
        int a = scan[tid];
        int b = (tid >= off) ? scan[tid - off] : 0;
        __syncthreads();
        scan[tid] = a + b;
        __syncthreads();
    }
    int pos   = scan[tid] - kc;
    int total = scan[255];

    #pragma unroll
    for (int i = 0; i < 8; ++i) {
        f32x4 cf0, cf1, mf0, mf1;
        #pragma unroll
        for (int j = 0; j < 8; ++j) {
            float cc = c[i][j];
            bool sel = (cc > thr_hi) || ((ov >> (i * 8 + j)) & 1ull);
            bool m_  = sel && (cc > 0.f);
            float cv = sel ? cc : 0.f;
            float mv = m_ ? 1.f : 0.f;
            if (j < 4) { cf0[j] = cv; mf0[j] = mv; }
            else       { cf1[j - 4] = cv; mf1[j - 4] = mv; }
            if (m_) {
                if (pos < CAP) {
                    idx_out[row * CAP + pos] = i * 2048 + tid * 8 + j;
                    val_out[row * CAP + pos] = cv;
                }
                ++pos;
            }
        }
        long o = base + i * 2048 + tid * 8;
        __builtin_nontemporal_store(cf0, (f32x4*)(codes + o));
        __builtin_nontemporal_store(cf1, (f32x4*)(codes + o + 4));
        __builtin_nontemporal_store(mf0, (f32x4*)(mask + o));
        __builtin_nontemporal_store(mf1, (f32x4*)(mask + o + 4));
    }
    if (tid == 0) cnt_out[row] = total < CAP ? total : CAP;
}

// ---------------------------------------------------------------------------
// K4: recon[b,:] = sum_j val_j * W_decT16[idx_j, :]   (f16 gather, f32 accum)
// ---------------------------------------------------------------------------
__global__ __launch_bounds__(256) void recon_sparse(const _Float16* __restrict__ Wd16,
                                                    const int* __restrict__ cnt,
                                                    const int* __restrict__ idx,
                                                    const float* __restrict__ val,
                                                    float* __restrict__ recon) {
    const int row = blockIdx.x;
    const int tid = threadIdx.x;
    __shared__ int   s_idx[CAP];
    __shared__ float s_val[CAP];
    const int n = cnt[row];
    for (int j = tid; j < n; j += 256) {
        s_idx[j] = idx[row * CAP + j];
        s_val[j] = val[row * CAP + j];
    }
    __syncthreads();

    float4 a0 = {0.f, 0.f, 0.f, 0.f};
    float4 a1 = {0.f, 0.f, 0.f, 0.f};
    for (int j = 0; j < n; ++j) {
        float c = s_val[j];
        const _Float16* w = Wd16 + (size_t)s_idx[j] * D_IN;
        f16x4 w0 = *(const f16x4*)(w + tid * 4);
        f16x4 w1 = *(const f16x4*)(w + 1024 + tid * 4);
        a0.x = fmaf(c, (float)w0[0], a0.x); a0.y = fmaf(c, (float)w0[1], a0.y);
        a0.z = fmaf(c, (float)w0[2], a0.z); a0.w = fmaf(c, (float)w0[3], a0.w);
        a1.x = fmaf(c, (float)w1[0], a1.x); a1.y = fmaf(c, (float)w1[1], a1.y);
        a1.z = fmaf(c, (float)w1[2], a1.z); a1.w = fmaf(c, (float)w1[3], a1.w);
    }
    float* out = recon + (size_t)row * D_IN;
    *(float4*)(out + tid * 4)        = a0;
    *(float4*)(out + 1024 + tid * 4) = a1;
}

// ---------------------------------------------------------------------------
// Workspace:
//  f16-raw path (needs ~216.3 MB):
//   [0,64M)    w_f16 (phase A) / W_decT f16 (phase B, after select)
//   [64M,80M)  x_f16
//   [80M,208M) raw f16 codes
//   [208M,..)  cnt (16K), idx (4M), val (4M)
//  fallback (ws too small, ~88.3 MB): raw f32 lives in d_out codes region,
//   cnt/idx/val at 80M.
// ---------------------------------------------------------------------------
extern "C" void kernel_launch(void* const* d_in, const int* in_sizes, int n_in,
                              void* d_out, int out_size, void* d_ws, size_t ws_size,
                              hipStream_t stream) {
    const float* x     = (const float*)d_in[0];
    const float* W_enc = (const float*)d_in[1];
    const float* b_enc = (const float*)d_in[2];
    const float* tau   = (const float*)d_in[3];
    const float* W_dec = (const float*)d_in[4];
    const int*   kptr  = (const int*)d_in[5];

    float* recon = (float*)d_out;
    float* codes = recon + (size_t)BATCH * D_IN;
    float* maskp = codes + (size_t)BATCH * D_SAE;

    char* w = (char*)d_ws;
    const size_t OFF_X   = (size_t)D_SAE * D_IN * 2;             // 64M
    const size_t OFF_RAW = OFF_X + (size_t)BATCH * D_IN * 2;     // 80M
    const size_t RAWSZ   = (size_t)BATCH * D_SAE * 2;            // 128M
    const size_t TAILSZ  = 16384 + 2 * (size_t)BATCH * CAP * 4;  // cnt+idx+val
    const bool f16raw = ws_size >= OFF_RAW + RAWSZ + TAILSZ;

    const size_t OFF_CNT = f16raw ? (OFF_RAW + RAWSZ) : OFF_RAW;
    ushort*   w_f16  = (ushort*)w;
    ushort*   x_f16  = (ushort*)(w + OFF_X);
    _Float16* W_decT = (_Float16*)w;                             // phase B
    int*      cnt    = (int*)  (w + OFF_CNT);
    int*      idxl   = (int*)  (w + OFF_CNT + 16384);
    float*    vall   = (float*)(w + OFF_CNT + 16384 + (size_t)BATCH * CAP * 4);
    void*     raw    = f16raw ? (void*)(w + OFF_RAW) : (void*)codes;

    hipLaunchKernelGGL(to_f16, dim3(1024), dim3(256), 0, stream,
                       x, x_f16, BATCH * D_IN / 4);
    hipLaunchKernelGGL(to_f16, dim3(4096), dim3(256), 0, stream,
                       W_enc, w_f16, D_SAE * D_IN / 4);
    if (f16raw) {
        hipLaunchKernelGGL((gemm_enc_mfma<1>), dim3(BATCH / 256, D_SAE / 256), dim3(512), 0, stream,
                           x_f16, w_f16, b_enc, tau, raw);
        hipLaunchKernelGGL((select_apply<1>), dim3(BATCH), dim3(256), 0, stream,
                           raw, codes, maskp, kptr, x, W_enc, b_enc, tau, cnt, idxl, vall);
    } else {
        hipLaunchKernelGGL((gemm_enc_mfma<0>), dim3(BATCH / 256, D_SAE / 256), dim3(512), 0, stream,
                           x_f16, w_f16, b_enc, tau, raw);
        hipLaunchKernelGGL((select_apply<0>), dim3(BATCH), dim3(256), 0, stream,
                           raw, codes, maskp, kptr, x, W_enc, b_enc, tau, cnt, idxl, vall);
    }
    hipLaunchKernelGGL(transpose_wdec_f16, dim3(D_SAE / 64, D_IN / 64), dim3(256), 0, stream,
                       W_dec, W_decT);
    hipLaunchKernelGGL(recon_sparse, dim3(BATCH), dim3(256), 0, stream,
                       W_decT, cnt, idxl, vall, recon);
}